// Round 8
// baseline (519.844 us; speedup 1.0000x reference)
//
#include <hip/hip_runtime.h>
#include <cstdint>
#include <cstddef>
#include <cstring>

#define TPB 256
#define TILE 4096

__device__ __forceinline__ ushort f2b(float f) {
    union { float f; uint32_t u; } v; v.f = f;
    uint32_t r = (v.u + 0x7FFFu + ((v.u >> 16) & 1u)) >> 16;
    return (ushort)r;
}
__device__ __forceinline__ float b2f(ushort h) {
    union { uint32_t u; float f; } v; v.u = ((uint32_t)h) << 16;
    return v.f;
}
__device__ __forceinline__ float b2f_lo(uint32_t u) {
    union { uint32_t u; float f; } v; v.u = u << 16;
    return v.f;
}
__device__ __forceinline__ float b2f_hi(uint32_t u) {
    union { uint32_t u; float f; } v; v.u = u & 0xFFFF0000u;
    return v.f;
}
__device__ __forceinline__ float f16lo2f(uint32_t u) {
    union { ushort s; _Float16 h; } v; v.s = (ushort)u;
    return (float)v.h;
}
__device__ __forceinline__ uint32_t pack_f16x2(float p0, float p1) {
    auto hp = __builtin_amdgcn_cvt_pkrtz(p0, p1);  // __fp16 ext_vector(2)
    uint32_t pk;
    __builtin_memcpy(&pk, &hp, 4);
    return pk;
}

// ================ CSR build: LDS-histogram radix partition (no global atomics) ================
// bucket = dst >> 8 (256 nodes per bucket). hist layout: hist[bucket * NBLK + tile]
// (bucket-major -> global exclusive scan gives stable partition regions).

__global__ __launch_bounds__(TPB) void k_hist(const int* __restrict__ dst, int* __restrict__ hist,
                                              int E, int NB, int NBLK) {
    __shared__ int hc[512];
    const int t = threadIdx.x, blk = blockIdx.x;
    for (int b = t; b < NB; b += TPB) hc[b] = 0;
    __syncthreads();
    const int e0 = blk * TILE;
    for (int i = t; i < TILE; i += TPB) {
        int e = e0 + i;
        if (e < E) atomicAdd(&hc[dst[e] >> 8], 1);
    }
    __syncthreads();
    for (int b = t; b < NB; b += TPB) hist[b * NBLK + blk] = hc[b];
}

__global__ __launch_bounds__(1024) void k_scanall(int* __restrict__ h, int ntot) {
    __shared__ int sh[1024];
    const int t = threadIdx.x;
    const int chunk = (ntot + 1023) >> 10;
    const int lo = t * chunk;
    const int hi = (lo + chunk < ntot) ? lo + chunk : ntot;
    int s = 0;
    for (int i = lo; i < hi; ++i) s += h[i];
    sh[t] = s;
    __syncthreads();
    for (int off = 1; off < 1024; off <<= 1) {
        int u = (t >= off) ? sh[t - off] : 0;
        __syncthreads();
        sh[t] += u;
        __syncthreads();
    }
    int run = sh[t] - s;  // exclusive base for this chunk
    for (int i = lo; i < hi; ++i) { int v = h[i]; h[i] = run; run += v; }
}

__global__ __launch_bounds__(TPB) void k_part(const int* __restrict__ src, const int* __restrict__ dst,
                                              const int* __restrict__ S, int* __restrict__ part,
                                              int E, int NB, int NBLK) {
    __shared__ int hbase[512];
    __shared__ int hcur[512];
    const int t = threadIdx.x, blk = blockIdx.x;
    for (int b = t; b < NB; b += TPB) { hbase[b] = S[b * NBLK + blk]; hcur[b] = 0; }
    __syncthreads();
    const int e0 = blk * TILE;
    for (int i = t; i < TILE; i += TPB) {
        int e = e0 + i;
        if (e < E) {
            int d = dst[e];
            int bu = d >> 8;
            int r = atomicAdd(&hcur[bu], 1);                 // LDS atomic (rank in region)
            part[hbase[bu] + r] = (src[e] << 8) | (d & 255); // src<2^17, fits 25 bits
        }
    }
}

__global__ __launch_bounds__(TPB) void k_csr(const int* __restrict__ part, const int* __restrict__ S,
                                             int* __restrict__ offs, int* __restrict__ csr,
                                             int E, int N, int NB, int NBLK) {
    __shared__ int cnt[256];
    __shared__ int pre[256];
    const int t = threadIdx.x, b = blockIdx.x;
    const int bstart = S[b * NBLK];
    const int bend = (b + 1 < NB) ? S[(b + 1) * NBLK] : E;
    cnt[t] = 0;
    __syncthreads();
    for (int e = bstart + t; e < bend; e += TPB) atomicAdd(&cnt[part[e] & 255], 1);
    __syncthreads();
    int c = cnt[t];
    pre[t] = c;
    __syncthreads();
    for (int off = 1; off < 256; off <<= 1) {
        int u = (t >= off) ? pre[t - off] : 0;
        __syncthreads();
        pre[t] += u;
        __syncthreads();
    }
    int ex = pre[t] - c;  // exclusive prefix within bucket
    int node = b * 256 + t;
    if (node <= N) offs[node] = bstart + ex;
    pre[t] = ex;          // repurpose as shared exclusive bases
    cnt[t] = 0;
    __syncthreads();
    for (int e = bstart + t; e < bend; e += TPB) {
        int pk = part[e];
        int local = pk & 255;
        int r = atomicAdd(&cnt[local], 1);   // LDS atomic
        csr[bstart + pre[local] + r] = pk >> 8;
    }
}

// ---------------- R = rho_w @ W0_pe ; cvec = rho_b @ W0_pe ----------------

__global__ __launch_bounds__(TPB) void k_rinit(const float* __restrict__ rho_w, const float* __restrict__ rho_b,
                                               const float* __restrict__ W0, float* __restrict__ R,
                                               float* __restrict__ cvec) {
    const float* Wpe = W0 + 128 * 64;  // rows 128..159 of W0
    int tid = threadIdx.x;
    for (int idx = tid; idx < 64 * 64; idx += TPB) {
        int r = idx >> 6, cc = idx & 63;
        float s = 0.f;
#pragma unroll
        for (int k = 0; k < 32; ++k) s = fmaf(rho_w[r * 32 + k], Wpe[k * 64 + cc], s);
        R[idx] = s;
    }
    if (tid < 64) {
        float s = 0.f;
#pragma unroll
        for (int k = 0; k < 32; ++k) s = fmaf(rho_b[k], Wpe[k * 64 + tid], s);
        cvec[tid] = s;
    }
}

// ---------------- fused SignNet ----------------

__global__ __launch_bounds__(TPB) void k_sign(const float* __restrict__ eig,
                                              const float* __restrict__ w1, const float* __restrict__ b1,
                                              const float* __restrict__ w2, const float* __restrict__ b2,
                                              ushort* __restrict__ S, int M) {
    __shared__ float eigS[64][9];
    __shared__ float w1s[512];
    __shared__ float b1s[64];
    __shared__ float Ap[64][65];
    __shared__ float Aq[64][65];
    __shared__ float Ws[64][64];
    const int tid = threadIdx.x;
    const int row0 = blockIdx.x * 64;

    for (int i = tid; i < 512; i += TPB) w1s[i] = w1[i];
    if (tid < 64) b1s[tid] = b1[tid];
    for (int i = tid; i < 1024; i += TPB) {
        float4 v = *(const float4*)(w2 + i * 4);
        Ws[0][i * 4 + 0] = v.x; Ws[0][i * 4 + 1] = v.y; Ws[0][i * 4 + 2] = v.z; Ws[0][i * 4 + 3] = v.w;
    }
    {
        int idx = tid * 2;
        int r = idx >> 3, c = idx & 7;
        int row = row0 + r; int rowc = row < M ? row : M - 1;
        float2 v = *(const float2*)(eig + (size_t)rowc * 8 + c);
        eigS[r][c] = v.x; eigS[r][c + 1] = v.y;
    }
    __syncthreads();

    {
        int r = tid >> 2, csub = tid & 3;
        float ev[8];
#pragma unroll
        for (int k = 0; k < 8; ++k) ev[k] = eigS[r][k];
#pragma unroll
        for (int c0 = 0; c0 < 16; ++c0) {
            int c = csub * 16 + c0;
            float t = 0.f;
#pragma unroll
            for (int k = 0; k < 8; ++k) t = fmaf(ev[k], w1s[k * 64 + c], t);
            float bb = b1s[c];
            Ap[c][r] = fmaxf(t + bb, 0.f);
            Aq[c][r] = fmaxf(bb - t, 0.f);
        }
    }
    __syncthreads();

    const int ty = tid >> 4, tx = tid & 15;
    float accp[4][4] = {{0.f}}, accq[4][4] = {{0.f}};
#pragma unroll 8
    for (int kk = 0; kk < 64; ++kk) {
        float ap[4], aq[4], bw[4];
#pragma unroll
        for (int i = 0; i < 4; ++i) { ap[i] = Ap[kk][ty * 4 + i]; aq[i] = Aq[kk][ty * 4 + i]; }
#pragma unroll
        for (int j = 0; j < 4; ++j) bw[j] = Ws[kk][tx * 4 + j];
#pragma unroll
        for (int i = 0; i < 4; ++i)
#pragma unroll
            for (int j = 0; j < 4; ++j) {
                accp[i][j] = fmaf(ap[i], bw[j], accp[i][j]);
                accq[i][j] = fmaf(aq[i], bw[j], accq[i][j]);
            }
    }
#pragma unroll
    for (int i = 0; i < 4; ++i) {
        int row = row0 + ty * 4 + i;
        if (row >= M) continue;
        ushort4 o;
        ushort* op = (ushort*)&o;
#pragma unroll
        for (int j = 0; j < 4; ++j) {
            int col = tx * 4 + j;
            float bb = b2[col];
            float v = fmaxf(accp[i][j] + bb, 0.f) + fmaxf(accq[i][j] + bb, 0.f);
            op[j] = f2b(v);
        }
        *(ushort4*)(S + (size_t)row * 64 + tx * 4) = o;
    }
}

// ---------------- main GEMM + fused alpha dot products ----------------

#define BM 64
#define BK 16

__global__ __launch_bounds__(TPB) void k_mm(const float* __restrict__ A1, int K1,
                                            const ushort* __restrict__ A2, int K2,
                                            const float* __restrict__ Wa, const float* __restrict__ Wb,
                                            const float* __restrict__ bias,
                                            const float* __restrict__ a_s, const float* __restrict__ a_d,
                                            float2* __restrict__ as2, float2* __restrict__ ad2,
                                            ushort* __restrict__ out, int M) {
    __shared__ float As[BK][BM + 4];
    __shared__ float Bs[BK][64];
    const int tid = threadIdx.x;
    const int row0 = blockIdx.x * BM;
    const int K = K1 + K2;
    const int ty = tid >> 4, tx = tid & 15;
    float acc[4][4] = {{0.f}};

    for (int k0 = 0; k0 < K; k0 += BK) {
        {
            int r = tid >> 2;
            int cq = (tid & 3) * 4;
            int row = row0 + r;
            int rowc = row < M ? row : M - 1;
            int c = k0 + cq;
            float4 v;
            if (c < K1) {
                v = *(const float4*)(A1 + (size_t)rowc * K1 + c);
            } else {
                const ushort* p = A2 + (size_t)rowc * K2 + (c - K1);
                ushort4 u = *(const ushort4*)p;
                v = make_float4(b2f(u.x), b2f(u.y), b2f(u.z), b2f(u.w));
            }
            As[cq + 0][r] = v.x; As[cq + 1][r] = v.y; As[cq + 2][r] = v.z; As[cq + 3][r] = v.w;
        }
        {
            int rr = tid >> 4;
            int cq2 = (tid & 15) * 4;
            int kk = k0 + rr;
            const float* Wrow = (kk < K1) ? (Wa + (size_t)kk * 64) : (Wb + (size_t)(kk - K1) * 64);
            float4 wv = *(const float4*)(Wrow + cq2);
            Bs[rr][cq2 + 0] = wv.x; Bs[rr][cq2 + 1] = wv.y; Bs[rr][cq2 + 2] = wv.z; Bs[rr][cq2 + 3] = wv.w;
        }
        __syncthreads();
#pragma unroll
        for (int kk = 0; kk < BK; ++kk) {
            float a[4], bw[4];
#pragma unroll
            for (int i = 0; i < 4; ++i) a[i] = As[kk][ty * 4 + i];
#pragma unroll
            for (int j = 0; j < 4; ++j) bw[j] = Bs[kk][tx * 4 + j];
#pragma unroll
            for (int i = 0; i < 4; ++i)
#pragma unroll
                for (int j = 0; j < 4; ++j)
                    acc[i][j] = fmaf(a[i], bw[j], acc[i][j]);
        }
        __syncthreads();
    }

    float s_acc[4] = {0.f, 0.f, 0.f, 0.f}, d_acc[4] = {0.f, 0.f, 0.f, 0.f};
#pragma unroll
    for (int i = 0; i < 4; ++i) {
#pragma unroll
        for (int j = 0; j < 4; ++j) {
            int col = tx * 4 + j;
            float v = acc[i][j];
            if (bias) v += bias[col];
            acc[i][j] = v;
            s_acc[i] = fmaf(v, a_s[col], s_acc[i]);
            d_acc[i] = fmaf(v, a_d[col], d_acc[i]);
        }
    }
#pragma unroll
    for (int m = 1; m <= 4; m <<= 1) {
#pragma unroll
        for (int i = 0; i < 4; ++i) {
            s_acc[i] += __shfl_xor(s_acc[i], m);
            d_acc[i] += __shfl_xor(d_acc[i], m);
        }
    }
    float s_oth[4], d_oth[4];
#pragma unroll
    for (int i = 0; i < 4; ++i) {
        s_oth[i] = __shfl_xor(s_acc[i], 8);
        d_oth[i] = __shfl_xor(d_acc[i], 8);
    }
#pragma unroll
    for (int i = 0; i < 4; ++i) {
        int row = row0 + ty * 4 + i;
        if (row >= M) continue;
        ushort4 o;
        ushort* op = (ushort*)&o;
#pragma unroll
        for (int j = 0; j < 4; ++j) op[j] = f2b(acc[i][j]);
        *(ushort4*)(out + (size_t)row * 64 + tx * 4) = o;
        if (tx == 0) {
            as2[row] = make_float2(s_acc[i], s_oth[i]);
            ad2[row] = make_float2(d_acc[i], d_oth[i]);
        }
    }
}

// ---------------- GAT aggregation: wave per dst, 4 edges/iteration ----------------

template <int DO_LN>
__global__ __launch_bounds__(TPB) void k_agg(const int* __restrict__ offs, const int* __restrict__ csr_src,
                                             const ushort* __restrict__ hb,
                                             const float2* __restrict__ as2,
                                             const float2* __restrict__ ad2,
                                             const float* __restrict__ bias,
                                             const float* __restrict__ ln_g,
                                             const float* __restrict__ ln_b,
                                             void* __restrict__ out_v, int M) {
    int w = (blockIdx.x * blockDim.x + threadIdx.x) >> 6;
    int lane = threadIdx.x & 63;
    if (w >= M) return;
    const int sub = lane & 15;       // lane within group
    const int grp = lane >> 4;       // group 0..3
    const int c0 = sub * 4;          // first of 4 owned channels
    const int head = sub >> 3;       // head of all 4 owned channels
    const int hshift = head << 4;    // 0 or 16

    float2 adv = ad2[w];
    int beg = offs[w], end = offs[w + 1];
    float a0 = 0.f, a1 = 0.f, a2 = 0.f, a3 = 0.f;
    float den0 = 0.f, den1 = 0.f;

    for (int base = beg; base < end; base += 64) {
        int nk = end - base;
        if (nk > 64) nk = 64;
        // ---- stage: one edge per lane ----
        int sidx = csr_src[base + (lane < nk ? lane : 0)];
        float2 av = as2[sidx];
        float e0 = av.x + adv.x; e0 = e0 > 0.f ? e0 : 0.2f * e0;
        float e1 = av.y + adv.y; e1 = e1 > 0.f ? e1 : 0.2f * e1;
        float p0 = __expf(e0), p1 = __expf(e1);
        if (lane >= nk) { p0 = 0.f; p1 = 0.f; }
        // den: order-free wave reduction
        float t0 = p0, t1 = p1;
#pragma unroll
        for (int m = 1; m <= 32; m <<= 1) {
            t0 += __shfl_xor(t0, m);
            t1 += __shfl_xor(t1, m);
        }
        den0 += t0; den1 += t1;
        uint32_t pk = pack_f16x2(p0, p1);

        // ---- inner: 8 edges per iteration (two 4-edge waves in flight) ----
        int j = 0;
        for (; j + 8 <= nk; j += 8) {
            int srcA = (j + grp) << 2;
            int srcB = (j + 4 + grp) << 2;
            int sA = __builtin_amdgcn_ds_bpermute(srcA, sidx);
            int sB = __builtin_amdgcn_ds_bpermute(srcB, sidx);
            uint32_t pA = (uint32_t)__builtin_amdgcn_ds_bpermute(srcA, (int)pk);
            uint32_t pB = (uint32_t)__builtin_amdgcn_ds_bpermute(srcB, (int)pk);
            uint2 uA = *(const uint2*)(hb + (size_t)(uint32_t)sA * 64u + c0);
            uint2 uB = *(const uint2*)(hb + (size_t)(uint32_t)sB * 64u + c0);
            float qA = f16lo2f(pA >> hshift);
            float qB = f16lo2f(pB >> hshift);
            a0 = fmaf(qA, b2f_lo(uA.x), a0);
            a1 = fmaf(qA, b2f_hi(uA.x), a1);
            a2 = fmaf(qA, b2f_lo(uA.y), a2);
            a3 = fmaf(qA, b2f_hi(uA.y), a3);
            a0 = fmaf(qB, b2f_lo(uB.x), a0);
            a1 = fmaf(qB, b2f_hi(uB.x), a1);
            a2 = fmaf(qB, b2f_lo(uB.y), a2);
            a3 = fmaf(qB, b2f_hi(uB.y), a3);
        }
        for (; j < nk; j += 4) {
            int src = j + grp;
            if (src > 63) src = 63;          // clamp; p=0 there if >= nk
            int s = __builtin_amdgcn_ds_bpermute(src << 2, sidx);
            uint32_t pe = (uint32_t)__builtin_amdgcn_ds_bpermute(src << 2, (int)pk);
            uint2 u = *(const uint2*)(hb + (size_t)(uint32_t)s * 64u + c0);
            float q = f16lo2f(pe >> hshift);
            a0 = fmaf(q, b2f_lo(u.x), a0);
            a1 = fmaf(q, b2f_hi(u.x), a1);
            a2 = fmaf(q, b2f_lo(u.y), a2);
            a3 = fmaf(q, b2f_hi(u.y), a3);
        }
    }
    // fold the 4 groups (lanes l, l+16, l+32, l+48 share channel set)
    a0 += __shfl_xor(a0, 16); a0 += __shfl_xor(a0, 32);
    a1 += __shfl_xor(a1, 16); a1 += __shfl_xor(a1, 32);
    a2 += __shfl_xor(a2, 16); a2 += __shfl_xor(a2, 32);
    a3 += __shfl_xor(a3, 16); a3 += __shfl_xor(a3, 32);

    float den = (head ? den1 : den0) + 1e-16f;
    float inv = 1.f / den;
    float4 bb = *(const float4*)(bias + c0);
    float o0 = fmaf(a0, inv, bb.x);
    float o1 = fmaf(a1, inv, bb.y);
    float o2 = fmaf(a2, inv, bb.z);
    float o3 = fmaf(a3, inv, bb.w);
    o0 = o0 > 0.f ? o0 : expm1f(o0);
    o1 = o1 > 0.f ? o1 : expm1f(o1);
    o2 = o2 > 0.f ? o2 : expm1f(o2);
    o3 = o3 > 0.f ? o3 : expm1f(o3);

    if (DO_LN) {
        float mu = o0 + o1 + o2 + o3;
#pragma unroll
        for (int m = 1; m <= 8; m <<= 1) mu += __shfl_xor(mu, m);
        mu *= (1.f / 64.f);
        float dv = (o0 - mu) * (o0 - mu) + (o1 - mu) * (o1 - mu)
                 + (o2 - mu) * (o2 - mu) + (o3 - mu) * (o3 - mu);
#pragma unroll
        for (int m = 1; m <= 8; m <<= 1) dv += __shfl_xor(dv, m);
        dv *= (1.f / 64.f);
        float rs = rsqrtf(dv + 1e-5f);
        float4 g = *(const float4*)(ln_g + c0);
        float4 b = *(const float4*)(ln_b + c0);
        o0 = (o0 - mu) * rs * g.x + b.x;
        o1 = (o1 - mu) * rs * g.y + b.y;
        o2 = (o2 - mu) * rs * g.z + b.z;
        o3 = (o3 - mu) * rs * g.w + b.w;
        if (lane < 16) {
            float4* out = (float4*)out_v;
            out[(size_t)w * 16 + sub] = make_float4(o0, o1, o2, o3);
        }
    } else {
        if (lane < 16) {
            uint2 pk2;
            pk2.x = (uint32_t)f2b(o0) | ((uint32_t)f2b(o1) << 16);
            pk2.y = (uint32_t)f2b(o2) | ((uint32_t)f2b(o3) << 16);
            uint2* out = (uint2*)out_v;
            out[(size_t)w * 16 + sub] = pk2;
        }
    }
}

// ---------------- launcher ----------------

extern "C" void kernel_launch(void* const* d_in, const int* in_sizes, int n_in,
                              void* d_out, int out_size, void* d_ws, size_t ws_size,
                              hipStream_t stream) {
    const float* x      = (const float*)d_in[0];
    const float* eig    = (const float*)d_in[1];
    const int*   ei     = (const int*)d_in[2];
    const float* phi_w1 = (const float*)d_in[3];
    const float* phi_b1 = (const float*)d_in[4];
    const float* phi_w2 = (const float*)d_in[5];
    const float* phi_b2 = (const float*)d_in[6];
    const float* rho_w  = (const float*)d_in[7];
    const float* rho_b  = (const float*)d_in[8];
    const float* W0     = (const float*)d_in[9];
    const float* asrc0  = (const float*)d_in[10];
    const float* adst0  = (const float*)d_in[11];
    const float* b0     = (const float*)d_in[12];
    const float* W1     = (const float*)d_in[13];
    const float* asrc1  = (const float*)d_in[14];
    const float* adst1  = (const float*)d_in[15];
    const float* b1     = (const float*)d_in[16];
    const float* ln_g   = (const float*)d_in[17];
    const float* ln_b   = (const float*)d_in[18];

    const int N = in_sizes[0] / 128;
    const int E = in_sizes[2] / 2;
    const int* esrc = ei;
    const int* edst = ei + E;

    const int NB   = (N >> 8) + 1;              // buckets of 256 nodes (covers sentinel N)
    const int NBLK = (E + TILE - 1) / TILE;     // edge tiles

    auto alignup = [](size_t v) { return (v + 255) & ~(size_t)255; };
    char* w = (char*)d_ws;
    int* S      = (int*)w; w += alignup((size_t)NB * NBLK * 4);   // hist -> scanned bases
    int* part   = (int*)w; w += alignup((size_t)E * 4);           // partitioned packed edges
    int* offs   = (int*)w; w += alignup((size_t)(N + 1) * 4);
    int* csr    = (int*)w; w += alignup((size_t)E * 4);
    ushort* Sb  = (ushort*)w; w += alignup((size_t)N * 64 * 2);   // SignNet output (bf16)
    ushort* hb  = (ushort*)w; w += alignup((size_t)N * 64 * 2);   // h0 / h1 bf16
    ushort* g0b = (ushort*)w; w += alignup((size_t)N * 64 * 2);   // layer-0 output bf16
    float2* as2 = (float2*)w; w += alignup((size_t)N * 8);
    float2* ad2 = (float2*)w; w += alignup((size_t)N * 8);
    float* R    = (float*)w; w += alignup(64 * 64 * 4);
    float* cvec = (float*)w; w += alignup(64 * 4);

    // ---- CSR build (radix partition, no global atomics) ----
    k_hist<<<NBLK, TPB, 0, stream>>>(edst, S, E, NB, NBLK);
    k_scanall<<<1, 1024, 0, stream>>>(S, NB * NBLK);
    k_part<<<NBLK, TPB, 0, stream>>>(esrc, edst, S, part, E, NB, NBLK);
    k_csr<<<NB, TPB, 0, stream>>>(part, S, offs, csr, E, N, NB, NBLK);

    k_rinit<<<1, TPB, 0, stream>>>(rho_w, rho_b, W0, R, cvec);

    int gM = (N + BM - 1) / BM;
    // ---- SignNet (fused phi1+phi2) ----
    k_sign<<<gM, TPB, 0, stream>>>(eig, phi_w1, phi_b1, phi_w2, phi_b2, Sb, N);

    // ---- GAT layer 0: h0 = x@W0[:128] + S@R + cvec -> hb (bf16), fused alpha ----
    k_mm<<<gM, TPB, 0, stream>>>(x, 128, Sb, 64, W0, R, cvec, asrc0, adst0, as2, ad2, hb, N);
    int ga = (N + 3) / 4;
    k_agg<0><<<ga, TPB, 0, stream>>>(offs, csr, hb, as2, ad2, b0, nullptr, nullptr, g0b, N);

    // ---- GAT layer 1: h1 = g0@W1 -> hb (bf16), fused alpha ----
    k_mm<<<gM, TPB, 0, stream>>>(nullptr, 0, g0b, 64, nullptr, W1, nullptr, asrc1, adst1, as2, ad2, hb, N);
    k_agg<1><<<ga, TPB, 0, stream>>>(offs, csr, hb, as2, ad2, b1, ln_g, ln_b, d_out, N);

    (void)n_in; (void)ws_size; (void)out_size;
}

// Round 9
// 289.043 us; speedup vs baseline: 1.7985x; 1.7985x over previous
//
#include <hip/hip_runtime.h>
#include <cstdint>
#include <cstddef>
#include <cstring>

#define TPB 256
#define TILE 8192

__device__ __forceinline__ ushort f2b(float f) {
    union { float f; uint32_t u; } v; v.f = f;
    uint32_t r = (v.u + 0x7FFFu + ((v.u >> 16) & 1u)) >> 16;
    return (ushort)r;
}
__device__ __forceinline__ float b2f(ushort h) {
    union { uint32_t u; float f; } v; v.u = ((uint32_t)h) << 16;
    return v.f;
}
__device__ __forceinline__ float b2f_lo(uint32_t u) {
    union { uint32_t u; float f; } v; v.u = u << 16;
    return v.f;
}
__device__ __forceinline__ float b2f_hi(uint32_t u) {
    union { uint32_t u; float f; } v; v.u = u & 0xFFFF0000u;
    return v.f;
}
__device__ __forceinline__ float f16lo2f(uint32_t u) {
    union { ushort s; _Float16 h; } v; v.s = (ushort)u;
    return (float)v.h;
}
__device__ __forceinline__ uint32_t pack_f16x2(float p0, float p1) {
    auto hp = __builtin_amdgcn_cvt_pkrtz(p0, p1);  // __fp16 ext_vector(2)
    uint32_t pk;
    __builtin_memcpy(&pk, &hp, 4);
    return pk;
}

// ================ CSR build: LDS-histogram radix partition (no global atomics) ================
// bucket = dst >> 8 (256 nodes per bucket). hist layout: hist[bucket * NBLK + tile]
// (bucket-major -> global exclusive scan gives stable partition regions).

__global__ __launch_bounds__(TPB) void k_hist(const int* __restrict__ dst, int* __restrict__ hist,
                                              int E, int NB, int NBLK) {
    __shared__ int hc[512];
    const int t = threadIdx.x, blk = blockIdx.x;
    for (int b = t; b < NB; b += TPB) hc[b] = 0;
    __syncthreads();
    const int e0 = blk * TILE;
    for (int i = t; i < TILE; i += TPB) {
        int e = e0 + i;
        if (e < E) atomicAdd(&hc[dst[e] >> 8], 1);
    }
    __syncthreads();
    for (int b = t; b < NB; b += TPB) hist[b * NBLK + blk] = hc[b];
}

// ---- multi-block exclusive scan (3 phases, in-place) ----

__global__ __launch_bounds__(TPB) void k_scan1(const int* __restrict__ a, int* __restrict__ bsum, int total) {
    __shared__ int sh[TPB];
    int base = blockIdx.x * 1024;
    int s = 0;
#pragma unroll
    for (int j = 0; j < 4; ++j) {
        int idx = base + threadIdx.x * 4 + j;
        if (idx < total) s += a[idx];
    }
    sh[threadIdx.x] = s;
    __syncthreads();
    for (int off = 128; off > 0; off >>= 1) {
        if (threadIdx.x < off) sh[threadIdx.x] += sh[threadIdx.x + off];
        __syncthreads();
    }
    if (threadIdx.x == 0) bsum[blockIdx.x] = sh[0];
}

__global__ void k_scan2(int* __restrict__ bsum, int nb) {
    __shared__ int sh[256];
    int t = threadIdx.x;
    int v = (t < nb) ? bsum[t] : 0;
    sh[t] = v;
    __syncthreads();
    for (int off = 1; off < 256; off <<= 1) {
        int u = (t >= off) ? sh[t - off] : 0;
        __syncthreads();
        sh[t] += u;
        __syncthreads();
    }
    if (t < nb) bsum[t] = sh[t] - v;  // exclusive
}

__global__ __launch_bounds__(TPB) void k_scan3(int* __restrict__ a, const int* __restrict__ bsum, int total) {
    __shared__ int sh[TPB];
    int base = blockIdx.x * 1024;
    int v[4];
    int s = 0;
#pragma unroll
    for (int j = 0; j < 4; ++j) {
        int idx = base + threadIdx.x * 4 + j;
        v[j] = (idx < total) ? a[idx] : 0;
        s += v[j];
    }
    sh[threadIdx.x] = s;
    __syncthreads();
    for (int off = 1; off < TPB; off <<= 1) {
        int t = (threadIdx.x >= off) ? sh[threadIdx.x - off] : 0;
        __syncthreads();
        sh[threadIdx.x] += t;
        __syncthreads();
    }
    int pre = bsum[blockIdx.x] + sh[threadIdx.x] - s;
#pragma unroll
    for (int j = 0; j < 4; ++j) {
        int idx = base + threadIdx.x * 4 + j;
        if (idx < total) { a[idx] = pre; pre += v[j]; }  // in-place: each idx owned by one thread
    }
}

__global__ __launch_bounds__(TPB) void k_part(const int* __restrict__ src, const int* __restrict__ dst,
                                              const int* __restrict__ S, int* __restrict__ part,
                                              int E, int NB, int NBLK) {
    __shared__ int hbase[512];
    __shared__ int hcur[512];
    const int t = threadIdx.x, blk = blockIdx.x;
    for (int b = t; b < NB; b += TPB) { hbase[b] = S[b * NBLK + blk]; hcur[b] = 0; }
    __syncthreads();
    const int e0 = blk * TILE;
    for (int i = t; i < TILE; i += TPB) {
        int e = e0 + i;
        if (e < E) {
            int d = dst[e];
            int bu = d >> 8;
            int r = atomicAdd(&hcur[bu], 1);                 // LDS atomic (rank in region)
            part[hbase[bu] + r] = (src[e] << 8) | (d & 255); // src<2^17, fits
        }
    }
}

__global__ __launch_bounds__(TPB) void k_csr(const int* __restrict__ part, const int* __restrict__ S,
                                             int* __restrict__ offs, int* __restrict__ csr,
                                             int E, int N, int NB, int NBLK) {
    __shared__ int cnt[256];
    __shared__ int pre[256];
    const int t = threadIdx.x, b = blockIdx.x;
    const int bstart = S[b * NBLK];
    const int bend = (b + 1 < NB) ? S[(b + 1) * NBLK] : E;
    cnt[t] = 0;
    __syncthreads();
    for (int e = bstart + t; e < bend; e += TPB) atomicAdd(&cnt[part[e] & 255], 1);
    __syncthreads();
    int c = cnt[t];
    pre[t] = c;
    __syncthreads();
    for (int off = 1; off < 256; off <<= 1) {
        int u = (t >= off) ? pre[t - off] : 0;
        __syncthreads();
        pre[t] += u;
        __syncthreads();
    }
    int ex = pre[t] - c;  // exclusive prefix within bucket
    int node = b * 256 + t;
    if (node <= N) offs[node] = bstart + ex;
    pre[t] = ex;          // repurpose as shared exclusive bases
    cnt[t] = 0;
    __syncthreads();
    for (int e = bstart + t; e < bend; e += TPB) {
        int pk = part[e];
        int local = pk & 255;
        int r = atomicAdd(&cnt[local], 1);   // LDS atomic
        csr[bstart + pre[local] + r] = pk >> 8;
    }
}

// ---------------- R = rho_w @ W0_pe ; cvec = rho_b @ W0_pe ----------------

__global__ __launch_bounds__(TPB) void k_rinit(const float* __restrict__ rho_w, const float* __restrict__ rho_b,
                                               const float* __restrict__ W0, float* __restrict__ R,
                                               float* __restrict__ cvec) {
    const float* Wpe = W0 + 128 * 64;  // rows 128..159 of W0
    int tid = threadIdx.x;
    for (int idx = tid; idx < 64 * 64; idx += TPB) {
        int r = idx >> 6, cc = idx & 63;
        float s = 0.f;
#pragma unroll
        for (int k = 0; k < 32; ++k) s = fmaf(rho_w[r * 32 + k], Wpe[k * 64 + cc], s);
        R[idx] = s;
    }
    if (tid < 64) {
        float s = 0.f;
#pragma unroll
        for (int k = 0; k < 32; ++k) s = fmaf(rho_b[k], Wpe[k * 64 + tid], s);
        cvec[tid] = s;
    }
}

// ---------------- fused SignNet ----------------

__global__ __launch_bounds__(TPB) void k_sign(const float* __restrict__ eig,
                                              const float* __restrict__ w1, const float* __restrict__ b1,
                                              const float* __restrict__ w2, const float* __restrict__ b2,
                                              ushort* __restrict__ S, int M) {
    __shared__ float eigS[64][9];
    __shared__ float w1s[512];
    __shared__ float b1s[64];
    __shared__ float Ap[64][65];
    __shared__ float Aq[64][65];
    __shared__ float Ws[64][64];
    const int tid = threadIdx.x;
    const int row0 = blockIdx.x * 64;

    for (int i = tid; i < 512; i += TPB) w1s[i] = w1[i];
    if (tid < 64) b1s[tid] = b1[tid];
    for (int i = tid; i < 1024; i += TPB) {
        float4 v = *(const float4*)(w2 + i * 4);
        Ws[0][i * 4 + 0] = v.x; Ws[0][i * 4 + 1] = v.y; Ws[0][i * 4 + 2] = v.z; Ws[0][i * 4 + 3] = v.w;
    }
    {
        int idx = tid * 2;
        int r = idx >> 3, c = idx & 7;
        int row = row0 + r; int rowc = row < M ? row : M - 1;
        float2 v = *(const float2*)(eig + (size_t)rowc * 8 + c);
        eigS[r][c] = v.x; eigS[r][c + 1] = v.y;
    }
    __syncthreads();

    {
        int r = tid >> 2, csub = tid & 3;
        float ev[8];
#pragma unroll
        for (int k = 0; k < 8; ++k) ev[k] = eigS[r][k];
#pragma unroll
        for (int c0 = 0; c0 < 16; ++c0) {
            int c = csub * 16 + c0;
            float t = 0.f;
#pragma unroll
            for (int k = 0; k < 8; ++k) t = fmaf(ev[k], w1s[k * 64 + c], t);
            float bb = b1s[c];
            Ap[c][r] = fmaxf(t + bb, 0.f);
            Aq[c][r] = fmaxf(bb - t, 0.f);
        }
    }
    __syncthreads();

    const int ty = tid >> 4, tx = tid & 15;
    float accp[4][4] = {{0.f}}, accq[4][4] = {{0.f}};
#pragma unroll 8
    for (int kk = 0; kk < 64; ++kk) {
        float ap[4], aq[4], bw[4];
#pragma unroll
        for (int i = 0; i < 4; ++i) { ap[i] = Ap[kk][ty * 4 + i]; aq[i] = Aq[kk][ty * 4 + i]; }
#pragma unroll
        for (int j = 0; j < 4; ++j) bw[j] = Ws[kk][tx * 4 + j];
#pragma unroll
        for (int i = 0; i < 4; ++i)
#pragma unroll
            for (int j = 0; j < 4; ++j) {
                accp[i][j] = fmaf(ap[i], bw[j], accp[i][j]);
                accq[i][j] = fmaf(aq[i], bw[j], accq[i][j]);
            }
    }
#pragma unroll
    for (int i = 0; i < 4; ++i) {
        int row = row0 + ty * 4 + i;
        if (row >= M) continue;
        ushort4 o;
        ushort* op = (ushort*)&o;
#pragma unroll
        for (int j = 0; j < 4; ++j) {
            int col = tx * 4 + j;
            float bb = b2[col];
            float v = fmaxf(accp[i][j] + bb, 0.f) + fmaxf(accq[i][j] + bb, 0.f);
            op[j] = f2b(v);
        }
        *(ushort4*)(S + (size_t)row * 64 + tx * 4) = o;
    }
}

// ---------------- main GEMM + fused alpha dot products ----------------

#define BM 64
#define BK 16

__global__ __launch_bounds__(TPB) void k_mm(const float* __restrict__ A1, int K1,
                                            const ushort* __restrict__ A2, int K2,
                                            const float* __restrict__ Wa, const float* __restrict__ Wb,
                                            const float* __restrict__ bias,
                                            const float* __restrict__ a_s, const float* __restrict__ a_d,
                                            float2* __restrict__ as2, float2* __restrict__ ad2,
                                            ushort* __restrict__ out, int M) {
    __shared__ float As[BK][BM + 4];
    __shared__ float Bs[BK][64];
    const int tid = threadIdx.x;
    const int row0 = blockIdx.x * BM;
    const int K = K1 + K2;
    const int ty = tid >> 4, tx = tid & 15;
    float acc[4][4] = {{0.f}};

    for (int k0 = 0; k0 < K; k0 += BK) {
        {
            int r = tid >> 2;
            int cq = (tid & 3) * 4;
            int row = row0 + r;
            int rowc = row < M ? row : M - 1;
            int c = k0 + cq;
            float4 v;
            if (c < K1) {
                v = *(const float4*)(A1 + (size_t)rowc * K1 + c);
            } else {
                const ushort* p = A2 + (size_t)rowc * K2 + (c - K1);
                ushort4 u = *(const ushort4*)p;
                v = make_float4(b2f(u.x), b2f(u.y), b2f(u.z), b2f(u.w));
            }
            As[cq + 0][r] = v.x; As[cq + 1][r] = v.y; As[cq + 2][r] = v.z; As[cq + 3][r] = v.w;
        }
        {
            int rr = tid >> 4;
            int cq2 = (tid & 15) * 4;
            int kk = k0 + rr;
            const float* Wrow = (kk < K1) ? (Wa + (size_t)kk * 64) : (Wb + (size_t)(kk - K1) * 64);
            float4 wv = *(const float4*)(Wrow + cq2);
            Bs[rr][cq2 + 0] = wv.x; Bs[rr][cq2 + 1] = wv.y; Bs[rr][cq2 + 2] = wv.z; Bs[rr][cq2 + 3] = wv.w;
        }
        __syncthreads();
#pragma unroll
        for (int kk = 0; kk < BK; ++kk) {
            float a[4], bw[4];
#pragma unroll
            for (int i = 0; i < 4; ++i) a[i] = As[kk][ty * 4 + i];
#pragma unroll
            for (int j = 0; j < 4; ++j) bw[j] = Bs[kk][tx * 4 + j];
#pragma unroll
            for (int i = 0; i < 4; ++i)
#pragma unroll
                for (int j = 0; j < 4; ++j)
                    acc[i][j] = fmaf(a[i], bw[j], acc[i][j]);
        }
        __syncthreads();
    }

    float s_acc[4] = {0.f, 0.f, 0.f, 0.f}, d_acc[4] = {0.f, 0.f, 0.f, 0.f};
#pragma unroll
    for (int i = 0; i < 4; ++i) {
#pragma unroll
        for (int j = 0; j < 4; ++j) {
            int col = tx * 4 + j;
            float v = acc[i][j];
            if (bias) v += bias[col];
            acc[i][j] = v;
            s_acc[i] = fmaf(v, a_s[col], s_acc[i]);
            d_acc[i] = fmaf(v, a_d[col], d_acc[i]);
        }
    }
#pragma unroll
    for (int m = 1; m <= 4; m <<= 1) {
#pragma unroll
        for (int i = 0; i < 4; ++i) {
            s_acc[i] += __shfl_xor(s_acc[i], m);
            d_acc[i] += __shfl_xor(d_acc[i], m);
        }
    }
    float s_oth[4], d_oth[4];
#pragma unroll
    for (int i = 0; i < 4; ++i) {
        s_oth[i] = __shfl_xor(s_acc[i], 8);
        d_oth[i] = __shfl_xor(d_acc[i], 8);
    }
#pragma unroll
    for (int i = 0; i < 4; ++i) {
        int row = row0 + ty * 4 + i;
        if (row >= M) continue;
        ushort4 o;
        ushort* op = (ushort*)&o;
#pragma unroll
        for (int j = 0; j < 4; ++j) op[j] = f2b(acc[i][j]);
        *(ushort4*)(out + (size_t)row * 64 + tx * 4) = o;
        if (tx == 0) {
            as2[row] = make_float2(s_acc[i], s_oth[i]);
            ad2[row] = make_float2(d_acc[i], d_oth[i]);
        }
    }
}

// ---------------- GAT aggregation: wave per dst, 4 edges/iteration ----------------

template <int DO_LN>
__global__ __launch_bounds__(TPB) void k_agg(const int* __restrict__ offs, const int* __restrict__ csr_src,
                                             const ushort* __restrict__ hb,
                                             const float2* __restrict__ as2,
                                             const float2* __restrict__ ad2,
                                             const float* __restrict__ bias,
                                             const float* __restrict__ ln_g,
                                             const float* __restrict__ ln_b,
                                             void* __restrict__ out_v, int M) {
    int w = (blockIdx.x * blockDim.x + threadIdx.x) >> 6;
    int lane = threadIdx.x & 63;
    if (w >= M) return;
    const int sub = lane & 15;       // lane within group
    const int grp = lane >> 4;       // group 0..3
    const int c0 = sub * 4;          // first of 4 owned channels
    const int head = sub >> 3;       // head of all 4 owned channels
    const int hshift = head << 4;    // 0 or 16

    float2 adv = ad2[w];
    int beg = offs[w], end = offs[w + 1];
    float a0 = 0.f, a1 = 0.f, a2 = 0.f, a3 = 0.f;
    float den0 = 0.f, den1 = 0.f;

    for (int base = beg; base < end; base += 64) {
        int nk = end - base;
        if (nk > 64) nk = 64;
        // ---- stage: one edge per lane ----
        int sidx = csr_src[base + (lane < nk ? lane : 0)];
        float2 av = as2[sidx];
        float e0 = av.x + adv.x; e0 = e0 > 0.f ? e0 : 0.2f * e0;
        float e1 = av.y + adv.y; e1 = e1 > 0.f ? e1 : 0.2f * e1;
        float p0 = __expf(e0), p1 = __expf(e1);
        if (lane >= nk) { p0 = 0.f; p1 = 0.f; }
        // den: order-free wave reduction
        float t0 = p0, t1 = p1;
#pragma unroll
        for (int m = 1; m <= 32; m <<= 1) {
            t0 += __shfl_xor(t0, m);
            t1 += __shfl_xor(t1, m);
        }
        den0 += t0; den1 += t1;
        uint32_t pk = pack_f16x2(p0, p1);

        // ---- inner: 8 edges per iteration (two 4-edge waves in flight) ----
        int j = 0;
        for (; j + 8 <= nk; j += 8) {
            int srcA = (j + grp) << 2;
            int srcB = (j + 4 + grp) << 2;
            int sA = __builtin_amdgcn_ds_bpermute(srcA, sidx);
            int sB = __builtin_amdgcn_ds_bpermute(srcB, sidx);
            uint32_t pA = (uint32_t)__builtin_amdgcn_ds_bpermute(srcA, (int)pk);
            uint32_t pB = (uint32_t)__builtin_amdgcn_ds_bpermute(srcB, (int)pk);
            uint2 uA = *(const uint2*)(hb + (size_t)(uint32_t)sA * 64u + c0);
            uint2 uB = *(const uint2*)(hb + (size_t)(uint32_t)sB * 64u + c0);
            float qA = f16lo2f(pA >> hshift);
            float qB = f16lo2f(pB >> hshift);
            a0 = fmaf(qA, b2f_lo(uA.x), a0);
            a1 = fmaf(qA, b2f_hi(uA.x), a1);
            a2 = fmaf(qA, b2f_lo(uA.y), a2);
            a3 = fmaf(qA, b2f_hi(uA.y), a3);
            a0 = fmaf(qB, b2f_lo(uB.x), a0);
            a1 = fmaf(qB, b2f_hi(uB.x), a1);
            a2 = fmaf(qB, b2f_lo(uB.y), a2);
            a3 = fmaf(qB, b2f_hi(uB.y), a3);
        }
        for (; j < nk; j += 4) {
            int src = j + grp;
            if (src > 63) src = 63;          // clamp; p=0 there if >= nk
            int s = __builtin_amdgcn_ds_bpermute(src << 2, sidx);
            uint32_t pe = (uint32_t)__builtin_amdgcn_ds_bpermute(src << 2, (int)pk);
            uint2 u = *(const uint2*)(hb + (size_t)(uint32_t)s * 64u + c0);
            float q = f16lo2f(pe >> hshift);
            a0 = fmaf(q, b2f_lo(u.x), a0);
            a1 = fmaf(q, b2f_hi(u.x), a1);
            a2 = fmaf(q, b2f_lo(u.y), a2);
            a3 = fmaf(q, b2f_hi(u.y), a3);
        }
    }
    // fold the 4 groups (lanes l, l+16, l+32, l+48 share channel set)
    a0 += __shfl_xor(a0, 16); a0 += __shfl_xor(a0, 32);
    a1 += __shfl_xor(a1, 16); a1 += __shfl_xor(a1, 32);
    a2 += __shfl_xor(a2, 16); a2 += __shfl_xor(a2, 32);
    a3 += __shfl_xor(a3, 16); a3 += __shfl_xor(a3, 32);

    float den = (head ? den1 : den0) + 1e-16f;
    float inv = 1.f / den;
    float4 bb = *(const float4*)(bias + c0);
    float o0 = fmaf(a0, inv, bb.x);
    float o1 = fmaf(a1, inv, bb.y);
    float o2 = fmaf(a2, inv, bb.z);
    float o3 = fmaf(a3, inv, bb.w);
    o0 = o0 > 0.f ? o0 : expm1f(o0);
    o1 = o1 > 0.f ? o1 : expm1f(o1);
    o2 = o2 > 0.f ? o2 : expm1f(o2);
    o3 = o3 > 0.f ? o3 : expm1f(o3);

    if (DO_LN) {
        float mu = o0 + o1 + o2 + o3;
#pragma unroll
        for (int m = 1; m <= 8; m <<= 1) mu += __shfl_xor(mu, m);
        mu *= (1.f / 64.f);
        float dv = (o0 - mu) * (o0 - mu) + (o1 - mu) * (o1 - mu)
                 + (o2 - mu) * (o2 - mu) + (o3 - mu) * (o3 - mu);
#pragma unroll
        for (int m = 1; m <= 8; m <<= 1) dv += __shfl_xor(dv, m);
        dv *= (1.f / 64.f);
        float rs = rsqrtf(dv + 1e-5f);
        float4 g = *(const float4*)(ln_g + c0);
        float4 b = *(const float4*)(ln_b + c0);
        o0 = (o0 - mu) * rs * g.x + b.x;
        o1 = (o1 - mu) * rs * g.y + b.y;
        o2 = (o2 - mu) * rs * g.z + b.z;
        o3 = (o3 - mu) * rs * g.w + b.w;
        if (lane < 16) {
            float4* out = (float4*)out_v;
            out[(size_t)w * 16 + sub] = make_float4(o0, o1, o2, o3);
        }
    } else {
        if (lane < 16) {
            uint2 pk2;
            pk2.x = (uint32_t)f2b(o0) | ((uint32_t)f2b(o1) << 16);
            pk2.y = (uint32_t)f2b(o2) | ((uint32_t)f2b(o3) << 16);
            uint2* out = (uint2*)out_v;
            out[(size_t)w * 16 + sub] = pk2;
        }
    }
}

// ---------------- launcher ----------------

extern "C" void kernel_launch(void* const* d_in, const int* in_sizes, int n_in,
                              void* d_out, int out_size, void* d_ws, size_t ws_size,
                              hipStream_t stream) {
    const float* x      = (const float*)d_in[0];
    const float* eig    = (const float*)d_in[1];
    const int*   ei     = (const int*)d_in[2];
    const float* phi_w1 = (const float*)d_in[3];
    const float* phi_b1 = (const float*)d_in[4];
    const float* phi_w2 = (const float*)d_in[5];
    const float* phi_b2 = (const float*)d_in[6];
    const float* rho_w  = (const float*)d_in[7];
    const float* rho_b  = (const float*)d_in[8];
    const float* W0     = (const float*)d_in[9];
    const float* asrc0  = (const float*)d_in[10];
    const float* adst0  = (const float*)d_in[11];
    const float* b0     = (const float*)d_in[12];
    const float* W1     = (const float*)d_in[13];
    const float* asrc1  = (const float*)d_in[14];
    const float* adst1  = (const float*)d_in[15];
    const float* b1     = (const float*)d_in[16];
    const float* ln_g   = (const float*)d_in[17];
    const float* ln_b   = (const float*)d_in[18];

    const int N = in_sizes[0] / 128;
    const int E = in_sizes[2] / 2;
    const int* esrc = ei;
    const int* edst = ei + E;

    const int NB   = (N >> 8) + 1;              // buckets of 256 nodes
    const int NBLK = (E + TILE - 1) / TILE;     // edge tiles

    auto alignup = [](size_t v) { return (v + 255) & ~(size_t)255; };
    char* w = (char*)d_ws;
    int* S      = (int*)w; w += alignup((size_t)NB * NBLK * 4);   // hist -> scanned bases
    int* bsum   = (int*)w; w += alignup(4096);
    int* part   = (int*)w; w += alignup((size_t)E * 4);           // partitioned packed edges
    int* offs   = (int*)w; w += alignup((size_t)(N + 1) * 4);
    int* csr    = (int*)w; w += alignup((size_t)E * 4);
    ushort* Sb  = (ushort*)w; w += alignup((size_t)N * 64 * 2);   // SignNet output (bf16)
    ushort* hb  = (ushort*)w; w += alignup((size_t)N * 64 * 2);   // h0 / h1 bf16
    ushort* g0b = (ushort*)w; w += alignup((size_t)N * 64 * 2);   // layer-0 output bf16
    float2* as2 = (float2*)w; w += alignup((size_t)N * 8);
    float2* ad2 = (float2*)w; w += alignup((size_t)N * 8);
    float* R    = (float*)w; w += alignup(64 * 64 * 4);
    float* cvec = (float*)w; w += alignup(64 * 4);

    // ---- CSR build (radix partition; multi-block scan) ----
    const int tot = NB * NBLK;
    const int nbS = (tot + 1023) / 1024;
    k_hist<<<NBLK, TPB, 0, stream>>>(edst, S, E, NB, NBLK);
    k_scan1<<<nbS, TPB, 0, stream>>>(S, bsum, tot);
    k_scan2<<<1, 256, 0, stream>>>(bsum, nbS);
    k_scan3<<<nbS, TPB, 0, stream>>>(S, bsum, tot);
    k_part<<<NBLK, TPB, 0, stream>>>(esrc, edst, S, part, E, NB, NBLK);
    k_csr<<<NB, TPB, 0, stream>>>(part, S, offs, csr, E, N, NB, NBLK);

    k_rinit<<<1, TPB, 0, stream>>>(rho_w, rho_b, W0, R, cvec);

    int gM = (N + BM - 1) / BM;
    // ---- SignNet (fused phi1+phi2) ----
    k_sign<<<gM, TPB, 0, stream>>>(eig, phi_w1, phi_b1, phi_w2, phi_b2, Sb, N);

    // ---- GAT layer 0: h0 = x@W0[:128] + S@R + cvec -> hb (bf16), fused alpha ----
    k_mm<<<gM, TPB, 0, stream>>>(x, 128, Sb, 64, W0, R, cvec, asrc0, adst0, as2, ad2, hb, N);
    int ga = (N + 3) / 4;
    k_agg<0><<<ga, TPB, 0, stream>>>(offs, csr, hb, as2, ad2, b0, nullptr, nullptr, g0b, N);

    // ---- GAT layer 1: h1 = g0@W1 -> hb (bf16), fused alpha ----
    k_mm<<<gM, TPB, 0, stream>>>(nullptr, 0, g0b, 64, nullptr, W1, nullptr, asrc1, adst1, as2, ad2, hb, N);
    k_agg<1><<<ga, TPB, 0, stream>>>(offs, csr, hb, as2, ad2, b1, ln_g, ln_b, d_out, N);

    (void)n_in; (void)ws_size; (void)out_size;
}

// Round 10
// 282.880 us; speedup vs baseline: 1.8377x; 1.0218x over previous
//
#include <hip/hip_runtime.h>
#include <cstdint>
#include <cstddef>
#include <cstring>

#define TPB 256
#define TILE 8192

typedef float f32x2 __attribute__((ext_vector_type(2)));

__device__ __forceinline__ ushort f2b(float f) {
    union { float f; uint32_t u; } v; v.f = f;
    uint32_t r = (v.u + 0x7FFFu + ((v.u >> 16) & 1u)) >> 16;
    return (ushort)r;
}
__device__ __forceinline__ float b2f(ushort h) {
    union { uint32_t u; float f; } v; v.u = ((uint32_t)h) << 16;
    return v.f;
}
__device__ __forceinline__ float b2f_lo(uint32_t u) {
    union { uint32_t u; float f; } v; v.u = u << 16;
    return v.f;
}
__device__ __forceinline__ float b2f_hi(uint32_t u) {
    union { uint32_t u; float f; } v; v.u = u & 0xFFFF0000u;
    return v.f;
}
__device__ __forceinline__ float f16lo2f(uint32_t u) {
    union { ushort s; _Float16 h; } v; v.s = (ushort)u;
    return (float)v.h;
}
__device__ __forceinline__ uint32_t pack_f16x2(float p0, float p1) {
    auto hp = __builtin_amdgcn_cvt_pkrtz(p0, p1);  // __fp16 ext_vector(2)
    uint32_t pk;
    __builtin_memcpy(&pk, &hp, 4);
    return pk;
}

// ================ CSR build: LDS-histogram radix partition (no global atomics) ================

__global__ __launch_bounds__(TPB) void k_hist(const int* __restrict__ dst, int* __restrict__ hist,
                                              int E, int NB, int NBLK) {
    __shared__ int hc[512];
    const int t = threadIdx.x, blk = blockIdx.x;
    for (int b = t; b < NB; b += TPB) hc[b] = 0;
    __syncthreads();
    const int e0 = blk * TILE;
    for (int i = t; i < TILE; i += TPB) {
        int e = e0 + i;
        if (e < E) atomicAdd(&hc[dst[e] >> 8], 1);
    }
    __syncthreads();
    for (int b = t; b < NB; b += TPB) hist[b * NBLK + blk] = hc[b];
}

// ---- multi-block exclusive scan (3 phases, in-place) ----

__global__ __launch_bounds__(TPB) void k_scan1(const int* __restrict__ a, int* __restrict__ bsum, int total) {
    __shared__ int sh[TPB];
    int base = blockIdx.x * 1024;
    int s = 0;
#pragma unroll
    for (int j = 0; j < 4; ++j) {
        int idx = base + threadIdx.x * 4 + j;
        if (idx < total) s += a[idx];
    }
    sh[threadIdx.x] = s;
    __syncthreads();
    for (int off = 128; off > 0; off >>= 1) {
        if (threadIdx.x < off) sh[threadIdx.x] += sh[threadIdx.x + off];
        __syncthreads();
    }
    if (threadIdx.x == 0) bsum[blockIdx.x] = sh[0];
}

__global__ void k_scan2(int* __restrict__ bsum, int nb) {
    __shared__ int sh[256];
    int t = threadIdx.x;
    int v = (t < nb) ? bsum[t] : 0;
    sh[t] = v;
    __syncthreads();
    for (int off = 1; off < 256; off <<= 1) {
        int u = (t >= off) ? sh[t - off] : 0;
        __syncthreads();
        sh[t] += u;
        __syncthreads();
    }
    if (t < nb) bsum[t] = sh[t] - v;  // exclusive
}

__global__ __launch_bounds__(TPB) void k_scan3(int* __restrict__ a, const int* __restrict__ bsum, int total) {
    __shared__ int sh[TPB];
    int base = blockIdx.x * 1024;
    int v[4];
    int s = 0;
#pragma unroll
    for (int j = 0; j < 4; ++j) {
        int idx = base + threadIdx.x * 4 + j;
        v[j] = (idx < total) ? a[idx] : 0;
        s += v[j];
    }
    sh[threadIdx.x] = s;
    __syncthreads();
    for (int off = 1; off < TPB; off <<= 1) {
        int t = (threadIdx.x >= off) ? sh[threadIdx.x - off] : 0;
        __syncthreads();
        sh[threadIdx.x] += t;
        __syncthreads();
    }
    int pre = bsum[blockIdx.x] + sh[threadIdx.x] - s;
#pragma unroll
    for (int j = 0; j < 4; ++j) {
        int idx = base + threadIdx.x * 4 + j;
        if (idx < total) { a[idx] = pre; pre += v[j]; }
    }
}

__global__ __launch_bounds__(TPB) void k_part(const int* __restrict__ src, const int* __restrict__ dst,
                                              const int* __restrict__ S, int* __restrict__ part,
                                              int E, int NB, int NBLK) {
    __shared__ int hbase[512];
    __shared__ int hcur[512];
    const int t = threadIdx.x, blk = blockIdx.x;
    for (int b = t; b < NB; b += TPB) { hbase[b] = S[b * NBLK + blk]; hcur[b] = 0; }
    __syncthreads();
    const int e0 = blk * TILE;
    for (int i = t; i < TILE; i += TPB) {
        int e = e0 + i;
        if (e < E) {
            int d = dst[e];
            int bu = d >> 8;
            int r = atomicAdd(&hcur[bu], 1);                 // LDS atomic
            part[hbase[bu] + r] = (src[e] << 8) | (d & 255);
        }
    }
}

__global__ __launch_bounds__(TPB) void k_csr(const int* __restrict__ part, const int* __restrict__ S,
                                             int* __restrict__ offs, int* __restrict__ csr,
                                             int E, int N, int NB, int NBLK) {
    __shared__ int cnt[256];
    __shared__ int pre[256];
    const int t = threadIdx.x, b = blockIdx.x;
    const int bstart = S[b * NBLK];
    const int bend = (b + 1 < NB) ? S[(b + 1) * NBLK] : E;
    cnt[t] = 0;
    __syncthreads();
    for (int e = bstart + t; e < bend; e += TPB) atomicAdd(&cnt[part[e] & 255], 1);
    __syncthreads();
    int c = cnt[t];
    pre[t] = c;
    __syncthreads();
    for (int off = 1; off < 256; off <<= 1) {
        int u = (t >= off) ? pre[t - off] : 0;
        __syncthreads();
        pre[t] += u;
        __syncthreads();
    }
    int ex = pre[t] - c;
    int node = b * 256 + t;
    if (node <= N) offs[node] = bstart + ex;
    pre[t] = ex;
    cnt[t] = 0;
    __syncthreads();
    for (int e = bstart + t; e < bend; e += TPB) {
        int pk = part[e];
        int local = pk & 255;
        int r = atomicAdd(&cnt[local], 1);   // LDS atomic
        csr[bstart + pre[local] + r] = pk >> 8;
    }
}

// ---------------- R = rho_w @ W0_pe ; cvec = rho_b @ W0_pe ----------------

__global__ __launch_bounds__(TPB) void k_rinit(const float* __restrict__ rho_w, const float* __restrict__ rho_b,
                                               const float* __restrict__ W0, float* __restrict__ R,
                                               float* __restrict__ cvec) {
    const float* Wpe = W0 + 128 * 64;
    int tid = threadIdx.x;
    for (int idx = tid; idx < 64 * 64; idx += TPB) {
        int r = idx >> 6, cc = idx & 63;
        float s = 0.f;
#pragma unroll
        for (int k = 0; k < 32; ++k) s = fmaf(rho_w[r * 32 + k], Wpe[k * 64 + cc], s);
        R[idx] = s;
    }
    if (tid < 64) {
        float s = 0.f;
#pragma unroll
        for (int k = 0; k < 32; ++k) s = fmaf(rho_b[k], Wpe[k * 64 + tid], s);
        cvec[tid] = s;
    }
}

// ---------------- fused SignNet ----------------

__global__ __launch_bounds__(TPB) void k_sign(const float* __restrict__ eig,
                                              const float* __restrict__ w1, const float* __restrict__ b1,
                                              const float* __restrict__ w2, const float* __restrict__ b2,
                                              ushort* __restrict__ S, int M) {
    __shared__ float eigS[64][9];
    __shared__ float w1s[512];
    __shared__ float b1s[64];
    __shared__ float Ap[64][65];
    __shared__ float Aq[64][65];
    __shared__ float Ws[64][64];
    const int tid = threadIdx.x;
    const int row0 = blockIdx.x * 64;

    for (int i = tid; i < 512; i += TPB) w1s[i] = w1[i];
    if (tid < 64) b1s[tid] = b1[tid];
    for (int i = tid; i < 1024; i += TPB) {
        float4 v = *(const float4*)(w2 + i * 4);
        Ws[0][i * 4 + 0] = v.x; Ws[0][i * 4 + 1] = v.y; Ws[0][i * 4 + 2] = v.z; Ws[0][i * 4 + 3] = v.w;
    }
    {
        int idx = tid * 2;
        int r = idx >> 3, c = idx & 7;
        int row = row0 + r; int rowc = row < M ? row : M - 1;
        float2 v = *(const float2*)(eig + (size_t)rowc * 8 + c);
        eigS[r][c] = v.x; eigS[r][c + 1] = v.y;
    }
    __syncthreads();

    {
        int r = tid >> 2, csub = tid & 3;
        float ev[8];
#pragma unroll
        for (int k = 0; k < 8; ++k) ev[k] = eigS[r][k];
#pragma unroll
        for (int c0 = 0; c0 < 16; ++c0) {
            int c = csub * 16 + c0;
            float t = 0.f;
#pragma unroll
            for (int k = 0; k < 8; ++k) t = fmaf(ev[k], w1s[k * 64 + c], t);
            float bb = b1s[c];
            Ap[c][r] = fmaxf(t + bb, 0.f);
            Aq[c][r] = fmaxf(bb - t, 0.f);
        }
    }
    __syncthreads();

    const int ty = tid >> 4, tx = tid & 15;
    float accp[4][4] = {{0.f}}, accq[4][4] = {{0.f}};
#pragma unroll 8
    for (int kk = 0; kk < 64; ++kk) {
        float ap[4], aq[4], bw[4];
#pragma unroll
        for (int i = 0; i < 4; ++i) { ap[i] = Ap[kk][ty * 4 + i]; aq[i] = Aq[kk][ty * 4 + i]; }
#pragma unroll
        for (int j = 0; j < 4; ++j) bw[j] = Ws[kk][tx * 4 + j];
#pragma unroll
        for (int i = 0; i < 4; ++i)
#pragma unroll
            for (int j = 0; j < 4; ++j) {
                accp[i][j] = fmaf(ap[i], bw[j], accp[i][j]);
                accq[i][j] = fmaf(aq[i], bw[j], accq[i][j]);
            }
    }
#pragma unroll
    for (int i = 0; i < 4; ++i) {
        int row = row0 + ty * 4 + i;
        if (row >= M) continue;
        ushort4 o;
        ushort* op = (ushort*)&o;
#pragma unroll
        for (int j = 0; j < 4; ++j) {
            int col = tx * 4 + j;
            float bb = b2[col];
            float v = fmaxf(accp[i][j] + bb, 0.f) + fmaxf(accq[i][j] + bb, 0.f);
            op[j] = f2b(v);
        }
        *(ushort4*)(S + (size_t)row * 64 + tx * 4) = o;
    }
}

// ---------------- main GEMM + fused alpha dot products ----------------

#define BM 64
#define BK 16

__global__ __launch_bounds__(TPB) void k_mm(const float* __restrict__ A1, int K1,
                                            const ushort* __restrict__ A2, int K2,
                                            const float* __restrict__ Wa, const float* __restrict__ Wb,
                                            const float* __restrict__ bias,
                                            const float* __restrict__ a_s, const float* __restrict__ a_d,
                                            float2* __restrict__ as2, float2* __restrict__ ad2,
                                            ushort* __restrict__ out, int M) {
    __shared__ float As[BK][BM + 4];
    __shared__ float Bs[BK][64];
    const int tid = threadIdx.x;
    const int row0 = blockIdx.x * BM;
    const int K = K1 + K2;
    const int ty = tid >> 4, tx = tid & 15;
    float acc[4][4] = {{0.f}};

    for (int k0 = 0; k0 < K; k0 += BK) {
        {
            int r = tid >> 2;
            int cq = (tid & 3) * 4;
            int row = row0 + r;
            int rowc = row < M ? row : M - 1;
            int c = k0 + cq;
            float4 v;
            if (c < K1) {
                v = *(const float4*)(A1 + (size_t)rowc * K1 + c);
            } else {
                const ushort* p = A2 + (size_t)rowc * K2 + (c - K1);
                ushort4 u = *(const ushort4*)p;
                v = make_float4(b2f(u.x), b2f(u.y), b2f(u.z), b2f(u.w));
            }
            As[cq + 0][r] = v.x; As[cq + 1][r] = v.y; As[cq + 2][r] = v.z; As[cq + 3][r] = v.w;
        }
        {
            int rr = tid >> 4;
            int cq2 = (tid & 15) * 4;
            int kk = k0 + rr;
            const float* Wrow = (kk < K1) ? (Wa + (size_t)kk * 64) : (Wb + (size_t)(kk - K1) * 64);
            float4 wv = *(const float4*)(Wrow + cq2);
            Bs[rr][cq2 + 0] = wv.x; Bs[rr][cq2 + 1] = wv.y; Bs[rr][cq2 + 2] = wv.z; Bs[rr][cq2 + 3] = wv.w;
        }
        __syncthreads();
#pragma unroll
        for (int kk = 0; kk < BK; ++kk) {
            float a[4], bw[4];
#pragma unroll
            for (int i = 0; i < 4; ++i) a[i] = As[kk][ty * 4 + i];
#pragma unroll
            for (int j = 0; j < 4; ++j) bw[j] = Bs[kk][tx * 4 + j];
#pragma unroll
            for (int i = 0; i < 4; ++i)
#pragma unroll
                for (int j = 0; j < 4; ++j)
                    acc[i][j] = fmaf(a[i], bw[j], acc[i][j]);
        }
        __syncthreads();
    }

    float s_acc[4] = {0.f, 0.f, 0.f, 0.f}, d_acc[4] = {0.f, 0.f, 0.f, 0.f};
#pragma unroll
    for (int i = 0; i < 4; ++i) {
#pragma unroll
        for (int j = 0; j < 4; ++j) {
            int col = tx * 4 + j;
            float v = acc[i][j];
            if (bias) v += bias[col];
            acc[i][j] = v;
            s_acc[i] = fmaf(v, a_s[col], s_acc[i]);
            d_acc[i] = fmaf(v, a_d[col], d_acc[i]);
        }
    }
#pragma unroll
    for (int m = 1; m <= 4; m <<= 1) {
#pragma unroll
        for (int i = 0; i < 4; ++i) {
            s_acc[i] += __shfl_xor(s_acc[i], m);
            d_acc[i] += __shfl_xor(d_acc[i], m);
        }
    }
    float s_oth[4], d_oth[4];
#pragma unroll
    for (int i = 0; i < 4; ++i) {
        s_oth[i] = __shfl_xor(s_acc[i], 8);
        d_oth[i] = __shfl_xor(d_acc[i], 8);
    }
#pragma unroll
    for (int i = 0; i < 4; ++i) {
        int row = row0 + ty * 4 + i;
        if (row >= M) continue;
        ushort4 o;
        ushort* op = (ushort*)&o;
#pragma unroll
        for (int j = 0; j < 4; ++j) op[j] = f2b(acc[i][j]);
        *(ushort4*)(out + (size_t)row * 64 + tx * 4) = o;
        if (tx == 0) {
            as2[row] = make_float2(s_acc[i], s_oth[i]);
            ad2[row] = make_float2(d_acc[i], d_oth[i]);
        }
    }
}

// ---------------- GAT aggregation ----------------
// wave per dst; 4 groups x 16 lanes; 4 channels/lane. Edge metadata {sidx,pk}
// staged in LDS (1 ds_write_b64/chunk), fetched with broadcast ds_read_b64.
// den folded into inner loop: each lane sums its group's f16 q weights; the
// group fold (shfl 16,32) yields the per-head denominator. float2 ext-vector
// accumulators -> v_pk_fma_f32.

template <int DO_LN>
__global__ __launch_bounds__(TPB) void k_agg(const int* __restrict__ offs, const int* __restrict__ csr_src,
                                             const ushort* __restrict__ hb,
                                             const float2* __restrict__ as2,
                                             const float2* __restrict__ ad2,
                                             const float* __restrict__ bias,
                                             const float* __restrict__ ln_g,
                                             const float* __restrict__ ln_b,
                                             void* __restrict__ out_v, int M) {
    __shared__ uint2 ep[4][64];          // per-wave edge metadata {sidx, pk}
    int w = (blockIdx.x * blockDim.x + threadIdx.x) >> 6;
    int lane = threadIdx.x & 63;
    int wl = threadIdx.x >> 6;
    if (w >= M) return;
    const int sub = lane & 15;
    const int grp = lane >> 4;
    const int c0 = sub * 4;
    const int head = sub >> 3;
    const int hshift = head << 4;

    float2 adv = ad2[w];
    int beg = offs[w], end = offs[w + 1];
    f32x2 acc01 = {0.f, 0.f}, acc23 = {0.f, 0.f};
    float qs = 0.f;                       // per-head denominator partial

    for (int base = beg; base < end; base += 64) {
        int nk = end - base;
        if (nk > 64) nk = 64;
        // ---- stage one edge per lane into LDS ----
        int sidx = csr_src[base + (lane < nk ? lane : 0)];
        float2 av = as2[sidx];
        float e0 = av.x + adv.x; e0 = e0 > 0.f ? e0 : 0.2f * e0;
        float e1 = av.y + adv.y; e1 = e1 > 0.f ? e1 : 0.2f * e1;
        float p0 = __expf(e0), p1 = __expf(e1);
        if (lane >= nk) { p0 = 0.f; p1 = 0.f; }
        ep[wl][lane] = make_uint2((uint32_t)sidx, pack_f16x2(p0, p1));

        int j = 0;
        for (; j + 8 <= nk; j += 8) {
            uint2 eA = ep[wl][j + grp];
            uint2 eB = ep[wl][j + 4 + grp];
            uint2 uA = *(const uint2*)(hb + ((uint32_t)eA.x << 6) + c0);
            uint2 uB = *(const uint2*)(hb + ((uint32_t)eB.x << 6) + c0);
            float qA = f16lo2f(eA.y >> hshift);
            float qB = f16lo2f(eB.y >> hshift);
            qs += qA + qB;
            f32x2 hA01 = {b2f_lo(uA.x), b2f_hi(uA.x)};
            f32x2 hA23 = {b2f_lo(uA.y), b2f_hi(uA.y)};
            f32x2 hB01 = {b2f_lo(uB.x), b2f_hi(uB.x)};
            f32x2 hB23 = {b2f_lo(uB.y), b2f_hi(uB.y)};
            acc01 += qA * hA01;
            acc23 += qA * hA23;
            acc01 += qB * hB01;
            acc23 += qB * hB23;
        }
        for (; j < nk; j += 4) {
            int src = j + grp;
            if (src > 63) src = 63;       // clamped lanes carry p=0
            uint2 e = ep[wl][src];
            uint2 u = *(const uint2*)(hb + ((uint32_t)e.x << 6) + c0);
            float q = f16lo2f(e.y >> hshift);
            qs += q;
            f32x2 h01 = {b2f_lo(u.x), b2f_hi(u.x)};
            f32x2 h23 = {b2f_lo(u.y), b2f_hi(u.y)};
            acc01 += q * h01;
            acc23 += q * h23;
        }
    }
    // fold the 4 groups (lanes l, l+16, l+32, l+48 share channel set & head)
    float a0 = acc01.x, a1 = acc01.y, a2 = acc23.x, a3 = acc23.y;
    a0 += __shfl_xor(a0, 16); a0 += __shfl_xor(a0, 32);
    a1 += __shfl_xor(a1, 16); a1 += __shfl_xor(a1, 32);
    a2 += __shfl_xor(a2, 16); a2 += __shfl_xor(a2, 32);
    a3 += __shfl_xor(a3, 16); a3 += __shfl_xor(a3, 32);
    qs += __shfl_xor(qs, 16); qs += __shfl_xor(qs, 32);

    float inv = 1.f / (qs + 1e-16f);
    float4 bb = *(const float4*)(bias + c0);
    float o0 = fmaf(a0, inv, bb.x);
    float o1 = fmaf(a1, inv, bb.y);
    float o2 = fmaf(a2, inv, bb.z);
    float o3 = fmaf(a3, inv, bb.w);
    o0 = o0 > 0.f ? o0 : expm1f(o0);
    o1 = o1 > 0.f ? o1 : expm1f(o1);
    o2 = o2 > 0.f ? o2 : expm1f(o2);
    o3 = o3 > 0.f ? o3 : expm1f(o3);

    if (DO_LN) {
        float mu = o0 + o1 + o2 + o3;
#pragma unroll
        for (int m = 1; m <= 8; m <<= 1) mu += __shfl_xor(mu, m);
        mu *= (1.f / 64.f);
        float dv = (o0 - mu) * (o0 - mu) + (o1 - mu) * (o1 - mu)
                 + (o2 - mu) * (o2 - mu) + (o3 - mu) * (o3 - mu);
#pragma unroll
        for (int m = 1; m <= 8; m <<= 1) dv += __shfl_xor(dv, m);
        dv *= (1.f / 64.f);
        float rs = rsqrtf(dv + 1e-5f);
        float4 g = *(const float4*)(ln_g + c0);
        float4 b = *(const float4*)(ln_b + c0);
        o0 = (o0 - mu) * rs * g.x + b.x;
        o1 = (o1 - mu) * rs * g.y + b.y;
        o2 = (o2 - mu) * rs * g.z + b.z;
        o3 = (o3 - mu) * rs * g.w + b.w;
        if (lane < 16) {
            float4* out = (float4*)out_v;
            out[(size_t)w * 16 + sub] = make_float4(o0, o1, o2, o3);
        }
    } else {
        if (lane < 16) {
            uint2 pk2;
            pk2.x = (uint32_t)f2b(o0) | ((uint32_t)f2b(o1) << 16);
            pk2.y = (uint32_t)f2b(o2) | ((uint32_t)f2b(o3) << 16);
            uint2* out = (uint2*)out_v;
            out[(size_t)w * 16 + sub] = pk2;
        }
    }
}

// ---------------- launcher ----------------

extern "C" void kernel_launch(void* const* d_in, const int* in_sizes, int n_in,
                              void* d_out, int out_size, void* d_ws, size_t ws_size,
                              hipStream_t stream) {
    const float* x      = (const float*)d_in[0];
    const float* eig    = (const float*)d_in[1];
    const int*   ei     = (const int*)d_in[2];
    const float* phi_w1 = (const float*)d_in[3];
    const float* phi_b1 = (const float*)d_in[4];
    const float* phi_w2 = (const float*)d_in[5];
    const float* phi_b2 = (const float*)d_in[6];
    const float* rho_w  = (const float*)d_in[7];
    const float* rho_b  = (const float*)d_in[8];
    const float* W0     = (const float*)d_in[9];
    const float* asrc0  = (const float*)d_in[10];
    const float* adst0  = (const float*)d_in[11];
    const float* b0     = (const float*)d_in[12];
    const float* W1     = (const float*)d_in[13];
    const float* asrc1  = (const float*)d_in[14];
    const float* adst1  = (const float*)d_in[15];
    const float* b1     = (const float*)d_in[16];
    const float* ln_g   = (const float*)d_in[17];
    const float* ln_b   = (const float*)d_in[18];

    const int N = in_sizes[0] / 128;
    const int E = in_sizes[2] / 2;
    const int* esrc = ei;
    const int* edst = ei + E;

    const int NB   = (N >> 8) + 1;
    const int NBLK = (E + TILE - 1) / TILE;

    auto alignup = [](size_t v) { return (v + 255) & ~(size_t)255; };
    char* w = (char*)d_ws;
    int* S      = (int*)w; w += alignup((size_t)NB * NBLK * 4);
    int* bsum   = (int*)w; w += alignup(4096);
    int* part   = (int*)w; w += alignup((size_t)E * 4);
    int* offs   = (int*)w; w += alignup((size_t)(N + 1) * 4);
    int* csr    = (int*)w; w += alignup((size_t)E * 4);
    ushort* Sb  = (ushort*)w; w += alignup((size_t)N * 64 * 2);
    ushort* hb  = (ushort*)w; w += alignup((size_t)N * 64 * 2);
    ushort* g0b = (ushort*)w; w += alignup((size_t)N * 64 * 2);
    float2* as2 = (float2*)w; w += alignup((size_t)N * 8);
    float2* ad2 = (float2*)w; w += alignup((size_t)N * 8);
    float* R    = (float*)w; w += alignup(64 * 64 * 4);
    float* cvec = (float*)w; w += alignup(64 * 4);

    // ---- CSR build (radix partition; multi-block scan) ----
    const int tot = NB * NBLK;
    const int nbS = (tot + 1023) / 1024;
    k_hist<<<NBLK, TPB, 0, stream>>>(edst, S, E, NB, NBLK);
    k_scan1<<<nbS, TPB, 0, stream>>>(S, bsum, tot);
    k_scan2<<<1, 256, 0, stream>>>(bsum, nbS);
    k_scan3<<<nbS, TPB, 0, stream>>>(S, bsum, tot);
    k_part<<<NBLK, TPB, 0, stream>>>(esrc, edst, S, part, E, NB, NBLK);
    k_csr<<<NB, TPB, 0, stream>>>(part, S, offs, csr, E, N, NB, NBLK);

    k_rinit<<<1, TPB, 0, stream>>>(rho_w, rho_b, W0, R, cvec);

    int gM = (N + BM - 1) / BM;
    // ---- SignNet (fused phi1+phi2) ----
    k_sign<<<gM, TPB, 0, stream>>>(eig, phi_w1, phi_b1, phi_w2, phi_b2, Sb, N);

    // ---- GAT layer 0 ----
    k_mm<<<gM, TPB, 0, stream>>>(x, 128, Sb, 64, W0, R, cvec, asrc0, adst0, as2, ad2, hb, N);
    int ga = (N + 3) / 4;
    k_agg<0><<<ga, TPB, 0, stream>>>(offs, csr, hb, as2, ad2, b0, nullptr, nullptr, g0b, N);

    // ---- GAT layer 1 ----
    k_mm<<<gM, TPB, 0, stream>>>(nullptr, 0, g0b, 64, nullptr, W1, nullptr, asrc1, adst1, as2, ad2, hb, N);
    k_agg<1><<<ga, TPB, 0, stream>>>(offs, csr, hb, as2, ad2, b1, ln_g, ln_b, d_out, N);

    (void)n_in; (void)ws_size; (void)out_size;
}

// Round 11
// 263.201 us; speedup vs baseline: 1.9751x; 1.0748x over previous
//
#include <hip/hip_runtime.h>
#include <cstdint>
#include <cstddef>
#include <cstring>

#define TPB 256
#define TILE 8192

typedef float f32x2 __attribute__((ext_vector_type(2)));
typedef float f32x4 __attribute__((ext_vector_type(4)));
typedef short short8_t __attribute__((ext_vector_type(8)));

__device__ __forceinline__ ushort f2b(float f) {
    union { float f; uint32_t u; } v; v.f = f;
    uint32_t r = (v.u + 0x7FFFu + ((v.u >> 16) & 1u)) >> 16;
    return (ushort)r;
}
__device__ __forceinline__ float b2f(ushort h) {
    union { uint32_t u; float f; } v; v.u = ((uint32_t)h) << 16;
    return v.f;
}
__device__ __forceinline__ float b2f_lo(uint32_t u) {
    union { uint32_t u; float f; } v; v.u = u << 16;
    return v.f;
}
__device__ __forceinline__ float b2f_hi(uint32_t u) {
    union { uint32_t u; float f; } v; v.u = u & 0xFFFF0000u;
    return v.f;
}
__device__ __forceinline__ float f16lo2f(uint32_t u) {
    union { ushort s; _Float16 h; } v; v.s = (ushort)u;
    return (float)v.h;
}
__device__ __forceinline__ uint32_t pack_f16x2(float p0, float p1) {
    auto hp = __builtin_amdgcn_cvt_pkrtz(p0, p1);
    uint32_t pk;
    __builtin_memcpy(&pk, &hp, 4);
    return pk;
}

// ================ CSR build: LDS-histogram radix partition ================

__global__ __launch_bounds__(TPB) void k_hist(const int* __restrict__ dst, int* __restrict__ hist,
                                              int E, int NB, int NBLK) {
    __shared__ int hc[512];
    const int t = threadIdx.x, blk = blockIdx.x;
    for (int b = t; b < NB; b += TPB) hc[b] = 0;
    __syncthreads();
    const int e0 = blk * TILE;
    for (int i = t; i < TILE; i += TPB) {
        int e = e0 + i;
        if (e < E) atomicAdd(&hc[dst[e] >> 8], 1);
    }
    __syncthreads();
    for (int b = t; b < NB; b += TPB) hist[b * NBLK + blk] = hc[b];
}

__global__ __launch_bounds__(TPB) void k_scan1(const int* __restrict__ a, int* __restrict__ bsum, int total) {
    __shared__ int sh[TPB];
    int base = blockIdx.x * 1024;
    int s = 0;
#pragma unroll
    for (int j = 0; j < 4; ++j) {
        int idx = base + threadIdx.x * 4 + j;
        if (idx < total) s += a[idx];
    }
    sh[threadIdx.x] = s;
    __syncthreads();
    for (int off = 128; off > 0; off >>= 1) {
        if (threadIdx.x < off) sh[threadIdx.x] += sh[threadIdx.x + off];
        __syncthreads();
    }
    if (threadIdx.x == 0) bsum[blockIdx.x] = sh[0];
}

__global__ void k_scan2(int* __restrict__ bsum, int nb) {
    __shared__ int sh[256];
    int t = threadIdx.x;
    int v = (t < nb) ? bsum[t] : 0;
    sh[t] = v;
    __syncthreads();
    for (int off = 1; off < 256; off <<= 1) {
        int u = (t >= off) ? sh[t - off] : 0;
        __syncthreads();
        sh[t] += u;
        __syncthreads();
    }
    if (t < nb) bsum[t] = sh[t] - v;
}

__global__ __launch_bounds__(TPB) void k_scan3(int* __restrict__ a, const int* __restrict__ bsum, int total) {
    __shared__ int sh[TPB];
    int base = blockIdx.x * 1024;
    int v[4];
    int s = 0;
#pragma unroll
    for (int j = 0; j < 4; ++j) {
        int idx = base + threadIdx.x * 4 + j;
        v[j] = (idx < total) ? a[idx] : 0;
        s += v[j];
    }
    sh[threadIdx.x] = s;
    __syncthreads();
    for (int off = 1; off < TPB; off <<= 1) {
        int t = (threadIdx.x >= off) ? sh[threadIdx.x - off] : 0;
        __syncthreads();
        sh[threadIdx.x] += t;
        __syncthreads();
    }
    int pre = bsum[blockIdx.x] + sh[threadIdx.x] - s;
#pragma unroll
    for (int j = 0; j < 4; ++j) {
        int idx = base + threadIdx.x * 4 + j;
        if (idx < total) { a[idx] = pre; pre += v[j]; }
    }
}

__global__ __launch_bounds__(TPB) void k_part(const int* __restrict__ src, const int* __restrict__ dst,
                                              const int* __restrict__ S, int* __restrict__ part,
                                              int E, int NB, int NBLK) {
    __shared__ int hbase[512];
    __shared__ int hcur[512];
    const int t = threadIdx.x, blk = blockIdx.x;
    for (int b = t; b < NB; b += TPB) { hbase[b] = S[b * NBLK + blk]; hcur[b] = 0; }
    __syncthreads();
    const int e0 = blk * TILE;
    for (int i = t; i < TILE; i += TPB) {
        int e = e0 + i;
        if (e < E) {
            int d = dst[e];
            int bu = d >> 8;
            int r = atomicAdd(&hcur[bu], 1);
            part[hbase[bu] + r] = (src[e] << 8) | (d & 255);
        }
    }
}

__global__ __launch_bounds__(TPB) void k_csr(const int* __restrict__ part, const int* __restrict__ S,
                                             int* __restrict__ offs, int* __restrict__ csr,
                                             int E, int N, int NB, int NBLK) {
    __shared__ int cnt[256];
    __shared__ int pre[256];
    const int t = threadIdx.x, b = blockIdx.x;
    const int bstart = S[b * NBLK];
    const int bend = (b + 1 < NB) ? S[(b + 1) * NBLK] : E;
    cnt[t] = 0;
    __syncthreads();
    for (int e = bstart + t; e < bend; e += TPB) atomicAdd(&cnt[part[e] & 255], 1);
    __syncthreads();
    int c = cnt[t];
    pre[t] = c;
    __syncthreads();
    for (int off = 1; off < 256; off <<= 1) {
        int u = (t >= off) ? pre[t - off] : 0;
        __syncthreads();
        pre[t] += u;
        __syncthreads();
    }
    int ex = pre[t] - c;
    int node = b * 256 + t;
    if (node <= N) offs[node] = bstart + ex;
    pre[t] = ex;
    cnt[t] = 0;
    __syncthreads();
    for (int e = bstart + t; e < bend; e += TPB) {
        int pk = part[e];
        int local = pk & 255;
        int r = atomicAdd(&cnt[local], 1);
        csr[bstart + pre[local] + r] = pk >> 8;
    }
}

// ---------------- R = rho_w @ W0_pe ; cvec = rho_b @ W0_pe ----------------

__global__ __launch_bounds__(TPB) void k_rinit(const float* __restrict__ rho_w, const float* __restrict__ rho_b,
                                               const float* __restrict__ W0, float* __restrict__ R,
                                               float* __restrict__ cvec) {
    const float* Wpe = W0 + 128 * 64;
    int tid = threadIdx.x;
    for (int idx = tid; idx < 64 * 64; idx += TPB) {
        int r = idx >> 6, cc = idx & 63;
        float s = 0.f;
#pragma unroll
        for (int k = 0; k < 32; ++k) s = fmaf(rho_w[r * 32 + k], Wpe[k * 64 + cc], s);
        R[idx] = s;
    }
    if (tid < 64) {
        float s = 0.f;
#pragma unroll
        for (int k = 0; k < 32; ++k) s = fmaf(rho_b[k], Wpe[k * 64 + tid], s);
        cvec[tid] = s;
    }
}

// ---------------- fused SignNet ----------------

__global__ __launch_bounds__(TPB) void k_sign(const float* __restrict__ eig,
                                              const float* __restrict__ w1, const float* __restrict__ b1,
                                              const float* __restrict__ w2, const float* __restrict__ b2,
                                              ushort* __restrict__ S, int M) {
    __shared__ float eigS[64][9];
    __shared__ float w1s[512];
    __shared__ float b1s[64];
    __shared__ float Ap[64][65];
    __shared__ float Aq[64][65];
    __shared__ float Ws[64][64];
    const int tid = threadIdx.x;
    const int row0 = blockIdx.x * 64;

    for (int i = tid; i < 512; i += TPB) w1s[i] = w1[i];
    if (tid < 64) b1s[tid] = b1[tid];
    for (int i = tid; i < 1024; i += TPB) {
        float4 v = *(const float4*)(w2 + i * 4);
        Ws[0][i * 4 + 0] = v.x; Ws[0][i * 4 + 1] = v.y; Ws[0][i * 4 + 2] = v.z; Ws[0][i * 4 + 3] = v.w;
    }
    {
        int idx = tid * 2;
        int r = idx >> 3, c = idx & 7;
        int row = row0 + r; int rowc = row < M ? row : M - 1;
        float2 v = *(const float2*)(eig + (size_t)rowc * 8 + c);
        eigS[r][c] = v.x; eigS[r][c + 1] = v.y;
    }
    __syncthreads();

    {
        int r = tid >> 2, csub = tid & 3;
        float ev[8];
#pragma unroll
        for (int k = 0; k < 8; ++k) ev[k] = eigS[r][k];
#pragma unroll
        for (int c0 = 0; c0 < 16; ++c0) {
            int c = csub * 16 + c0;
            float t = 0.f;
#pragma unroll
            for (int k = 0; k < 8; ++k) t = fmaf(ev[k], w1s[k * 64 + c], t);
            float bb = b1s[c];
            Ap[c][r] = fmaxf(t + bb, 0.f);
            Aq[c][r] = fmaxf(bb - t, 0.f);
        }
    }
    __syncthreads();

    const int ty = tid >> 4, tx = tid & 15;
    float accp[4][4] = {{0.f}}, accq[4][4] = {{0.f}};
#pragma unroll 8
    for (int kk = 0; kk < 64; ++kk) {
        float ap[4], aq[4], bw[4];
#pragma unroll
        for (int i = 0; i < 4; ++i) { ap[i] = Ap[kk][ty * 4 + i]; aq[i] = Aq[kk][ty * 4 + i]; }
#pragma unroll
        for (int j = 0; j < 4; ++j) bw[j] = Ws[kk][tx * 4 + j];
#pragma unroll
        for (int i = 0; i < 4; ++i)
#pragma unroll
            for (int j = 0; j < 4; ++j) {
                accp[i][j] = fmaf(ap[i], bw[j], accp[i][j]);
                accq[i][j] = fmaf(aq[i], bw[j], accq[i][j]);
            }
    }
#pragma unroll
    for (int i = 0; i < 4; ++i) {
        int row = row0 + ty * 4 + i;
        if (row >= M) continue;
        ushort4 o;
        ushort* op = (ushort*)&o;
#pragma unroll
        for (int j = 0; j < 4; ++j) {
            int col = tx * 4 + j;
            float bb = b2[col];
            float v = fmaxf(accp[i][j] + bb, 0.f) + fmaxf(accq[i][j] + bb, 0.f);
            op[j] = f2b(v);
        }
        *(ushort4*)(S + (size_t)row * 64 + tx * 4) = o;
    }
}

// ---------------- MFMA GEMM + fused alpha ----------------
// out[M,64] = bf16( [A1_f32(K1)|A2_bf16(K2)] @ [Wa;Wb] + bias ), alpha dots fused.
// Block: 64 rows x 64 cols, 4 waves; wave w owns rows 16w..16w+15.
// A-frag: row=lane&15, k=(lane>>4)*8+j ; B-frag: col=lane&15, same k (Wt stored [col][k]).
// C/D: col=lane&15, row=(lane>>4)*4+reg  [m89-verified].

template <int K1, int K2>
__global__ __launch_bounds__(TPB) void k_mmfma(const float* __restrict__ A1,
                                               const ushort* __restrict__ A2,
                                               const float* __restrict__ Wa, const float* __restrict__ Wb,
                                               const float* __restrict__ bias,
                                               const float* __restrict__ a_s, const float* __restrict__ a_d,
                                               float2* __restrict__ as2, float2* __restrict__ ad2,
                                               ushort* __restrict__ out, int M) {
    constexpr int K = K1 + K2;
    constexpr int KP = K + 8;                    // pad: row stride (K+8)*2B, 16B-divisible
    __shared__ __align__(16) ushort Ab[64 * KP];
    __shared__ __align__(16) ushort Wt[64 * KP];
    const int tid = threadIdx.x;
    const int row0 = blockIdx.x * 64;

    // ---- stage A (fp32 -> bf16) ----
    if constexpr (K1 > 0) {
        for (int idx = tid; idx < 64 * K1 / 4; idx += TPB) {
            int r = idx / (K1 / 4);
            int c4 = (idx % (K1 / 4)) * 4;
            int row = row0 + r; int rowc = row < M ? row : M - 1;
            float4 v = *(const float4*)(A1 + (size_t)rowc * K1 + c4);
            Ab[r * KP + c4 + 0] = f2b(v.x);
            Ab[r * KP + c4 + 1] = f2b(v.y);
            Ab[r * KP + c4 + 2] = f2b(v.z);
            Ab[r * KP + c4 + 3] = f2b(v.w);
        }
    }
    if constexpr (K2 > 0) {
        for (int idx = tid; idx < 64 * K2 / 4; idx += TPB) {
            int r = idx / (K2 / 4);
            int c4 = (idx % (K2 / 4)) * 4;
            int row = row0 + r; int rowc = row < M ? row : M - 1;
            ushort4 u = *(const ushort4*)(A2 + (size_t)rowc * K2 + c4);
            Ab[r * KP + K1 + c4 + 0] = u.x;
            Ab[r * KP + K1 + c4 + 1] = u.y;
            Ab[r * KP + K1 + c4 + 2] = u.z;
            Ab[r * KP + K1 + c4 + 3] = u.w;
        }
    }
    // ---- stage W transposed: Wt[c*KP + k] = bf16(W[k][c]) ----
    for (int idx = tid; idx < K * 16; idx += TPB) {
        int k = idx / 16;
        int c4 = (idx % 16) * 4;
        const float* Wrow = (K1 > 0 && k < K1) ? (Wa + (size_t)k * 64) : (Wb + (size_t)(k - K1) * 64);
        float4 v = *(const float4*)(Wrow + c4);
        Wt[(c4 + 0) * KP + k] = f2b(v.x);
        Wt[(c4 + 1) * KP + k] = f2b(v.y);
        Wt[(c4 + 2) * KP + k] = f2b(v.z);
        Wt[(c4 + 3) * KP + k] = f2b(v.w);
    }
    __syncthreads();

    const int w = tid >> 6, lane = tid & 63;
    const int lr = lane & 15, kg = lane >> 4;
    f32x4 acc0 = {0.f, 0.f, 0.f, 0.f}, acc1 = acc0, acc2 = acc0, acc3 = acc0;
    const ushort* arow = &Ab[(w * 16 + lr) * KP + kg * 8];
    const ushort* bp0 = &Wt[(0 + lr) * KP + kg * 8];
    const ushort* bp1 = &Wt[(16 + lr) * KP + kg * 8];
    const ushort* bp2 = &Wt[(32 + lr) * KP + kg * 8];
    const ushort* bp3 = &Wt[(48 + lr) * KP + kg * 8];
#pragma unroll
    for (int k0 = 0; k0 < K; k0 += 32) {
        short8_t af = *(const short8_t*)(arow + k0);
        short8_t b0 = *(const short8_t*)(bp0 + k0);
        short8_t b1 = *(const short8_t*)(bp1 + k0);
        short8_t b2 = *(const short8_t*)(bp2 + k0);
        short8_t b3 = *(const short8_t*)(bp3 + k0);
        acc0 = __builtin_amdgcn_mfma_f32_16x16x32_bf16(af, b0, acc0, 0, 0, 0);
        acc1 = __builtin_amdgcn_mfma_f32_16x16x32_bf16(af, b1, acc1, 0, 0, 0);
        acc2 = __builtin_amdgcn_mfma_f32_16x16x32_bf16(af, b2, acc2, 0, 0, 0);
        acc3 = __builtin_amdgcn_mfma_f32_16x16x32_bf16(af, b3, acc3, 0, 0, 0);
    }

    // ---- epilogue: bias, store, fused alpha dots ----
    float asr0 = a_s[lr], asr1 = a_s[16 + lr], asr2 = a_s[32 + lr], asr3 = a_s[48 + lr];
    float adr0 = a_d[lr], adr1 = a_d[16 + lr], adr2 = a_d[32 + lr], adr3 = a_d[48 + lr];
    float bb0 = 0.f, bb1 = 0.f, bb2 = 0.f, bb3 = 0.f;
    if (bias) { bb0 = bias[lr]; bb1 = bias[16 + lr]; bb2 = bias[32 + lr]; bb3 = bias[48 + lr]; }

#pragma unroll
    for (int i = 0; i < 4; ++i) {
        int row = row0 + w * 16 + kg * 4 + i;
        float v0 = acc0[i] + bb0;
        float v1 = acc1[i] + bb1;
        float v2 = acc2[i] + bb2;
        float v3 = acc3[i] + bb3;
        float sh0 = fmaf(v0, asr0, v1 * asr1);
        float sh1 = fmaf(v2, asr2, v3 * asr3);
        float dh0 = fmaf(v0, adr0, v1 * adr1);
        float dh1 = fmaf(v2, adr2, v3 * adr3);
#pragma unroll
        for (int m = 1; m <= 8; m <<= 1) {
            sh0 += __shfl_xor(sh0, m);
            sh1 += __shfl_xor(sh1, m);
            dh0 += __shfl_xor(dh0, m);
            dh1 += __shfl_xor(dh1, m);
        }
        if (row < M) {
            ushort* orow = out + (size_t)row * 64 + lr;
            orow[0]  = f2b(v0);
            orow[16] = f2b(v1);
            orow[32] = f2b(v2);
            orow[48] = f2b(v3);
            if (lr == 0) {
                as2[row] = make_float2(sh0, sh1);
                ad2[row] = make_float2(dh0, dh1);
            }
        }
    }
}

// ---------------- GAT aggregation (unchanged from round 10) ----------------

template <int DO_LN>
__global__ __launch_bounds__(TPB) void k_agg(const int* __restrict__ offs, const int* __restrict__ csr_src,
                                             const ushort* __restrict__ hb,
                                             const float2* __restrict__ as2,
                                             const float2* __restrict__ ad2,
                                             const float* __restrict__ bias,
                                             const float* __restrict__ ln_g,
                                             const float* __restrict__ ln_b,
                                             void* __restrict__ out_v, int M) {
    __shared__ uint2 ep[4][64];
    int w = (blockIdx.x * blockDim.x + threadIdx.x) >> 6;
    int lane = threadIdx.x & 63;
    int wl = threadIdx.x >> 6;
    if (w >= M) return;
    const int sub = lane & 15;
    const int grp = lane >> 4;
    const int c0 = sub * 4;
    const int head = sub >> 3;
    const int hshift = head << 4;

    float2 adv = ad2[w];
    int beg = offs[w], end = offs[w + 1];
    f32x2 acc01 = {0.f, 0.f}, acc23 = {0.f, 0.f};
    float qs = 0.f;

    for (int base = beg; base < end; base += 64) {
        int nk = end - base;
        if (nk > 64) nk = 64;
        int sidx = csr_src[base + (lane < nk ? lane : 0)];
        float2 av = as2[sidx];
        float e0 = av.x + adv.x; e0 = e0 > 0.f ? e0 : 0.2f * e0;
        float e1 = av.y + adv.y; e1 = e1 > 0.f ? e1 : 0.2f * e1;
        float p0 = __expf(e0), p1 = __expf(e1);
        if (lane >= nk) { p0 = 0.f; p1 = 0.f; }
        ep[wl][lane] = make_uint2((uint32_t)sidx, pack_f16x2(p0, p1));

        int j = 0;
        for (; j + 8 <= nk; j += 8) {
            uint2 eA = ep[wl][j + grp];
            uint2 eB = ep[wl][j + 4 + grp];
            uint2 uA = *(const uint2*)(hb + ((uint32_t)eA.x << 6) + c0);
            uint2 uB = *(const uint2*)(hb + ((uint32_t)eB.x << 6) + c0);
            float qA = f16lo2f(eA.y >> hshift);
            float qB = f16lo2f(eB.y >> hshift);
            qs += qA + qB;
            f32x2 hA01 = {b2f_lo(uA.x), b2f_hi(uA.x)};
            f32x2 hA23 = {b2f_lo(uA.y), b2f_hi(uA.y)};
            f32x2 hB01 = {b2f_lo(uB.x), b2f_hi(uB.x)};
            f32x2 hB23 = {b2f_lo(uB.y), b2f_hi(uB.y)};
            acc01 += qA * hA01;
            acc23 += qA * hA23;
            acc01 += qB * hB01;
            acc23 += qB * hB23;
        }
        for (; j < nk; j += 4) {
            int src = j + grp;
            if (src > 63) src = 63;
            uint2 e = ep[wl][src];
            uint2 u = *(const uint2*)(hb + ((uint32_t)e.x << 6) + c0);
            float q = f16lo2f(e.y >> hshift);
            qs += q;
            f32x2 h01 = {b2f_lo(u.x), b2f_hi(u.x)};
            f32x2 h23 = {b2f_lo(u.y), b2f_hi(u.y)};
            acc01 += q * h01;
            acc23 += q * h23;
        }
    }
    float a0 = acc01.x, a1 = acc01.y, a2 = acc23.x, a3 = acc23.y;
    a0 += __shfl_xor(a0, 16); a0 += __shfl_xor(a0, 32);
    a1 += __shfl_xor(a1, 16); a1 += __shfl_xor(a1, 32);
    a2 += __shfl_xor(a2, 16); a2 += __shfl_xor(a2, 32);
    a3 += __shfl_xor(a3, 16); a3 += __shfl_xor(a3, 32);
    qs += __shfl_xor(qs, 16); qs += __shfl_xor(qs, 32);

    float inv = 1.f / (qs + 1e-16f);
    float4 bb = *(const float4*)(bias + c0);
    float o0 = fmaf(a0, inv, bb.x);
    float o1 = fmaf(a1, inv, bb.y);
    float o2 = fmaf(a2, inv, bb.z);
    float o3 = fmaf(a3, inv, bb.w);
    o0 = o0 > 0.f ? o0 : expm1f(o0);
    o1 = o1 > 0.f ? o1 : expm1f(o1);
    o2 = o2 > 0.f ? o2 : expm1f(o2);
    o3 = o3 > 0.f ? o3 : expm1f(o3);

    if (DO_LN) {
        float mu = o0 + o1 + o2 + o3;
#pragma unroll
        for (int m = 1; m <= 8; m <<= 1) mu += __shfl_xor(mu, m);
        mu *= (1.f / 64.f);
        float dv = (o0 - mu) * (o0 - mu) + (o1 - mu) * (o1 - mu)
                 + (o2 - mu) * (o2 - mu) + (o3 - mu) * (o3 - mu);
#pragma unroll
        for (int m = 1; m <= 8; m <<= 1) dv += __shfl_xor(dv, m);
        dv *= (1.f / 64.f);
        float rs = rsqrtf(dv + 1e-5f);
        float4 g = *(const float4*)(ln_g + c0);
        float4 b = *(const float4*)(ln_b + c0);
        o0 = (o0 - mu) * rs * g.x + b.x;
        o1 = (o1 - mu) * rs * g.y + b.y;
        o2 = (o2 - mu) * rs * g.z + b.z;
        o3 = (o3 - mu) * rs * g.w + b.w;
        if (lane < 16) {
            float4* out = (float4*)out_v;
            out[(size_t)w * 16 + sub] = make_float4(o0, o1, o2, o3);
        }
    } else {
        if (lane < 16) {
            uint2 pk2;
            pk2.x = (uint32_t)f2b(o0) | ((uint32_t)f2b(o1) << 16);
            pk2.y = (uint32_t)f2b(o2) | ((uint32_t)f2b(o3) << 16);
            uint2* out = (uint2*)out_v;
            out[(size_t)w * 16 + sub] = pk2;
        }
    }
}

// ---------------- launcher ----------------

extern "C" void kernel_launch(void* const* d_in, const int* in_sizes, int n_in,
                              void* d_out, int out_size, void* d_ws, size_t ws_size,
                              hipStream_t stream) {
    const float* x      = (const float*)d_in[0];
    const float* eig    = (const float*)d_in[1];
    const int*   ei     = (const int*)d_in[2];
    const float* phi_w1 = (const float*)d_in[3];
    const float* phi_b1 = (const float*)d_in[4];
    const float* phi_w2 = (const float*)d_in[5];
    const float* phi_b2 = (const float*)d_in[6];
    const float* rho_w  = (const float*)d_in[7];
    const float* rho_b  = (const float*)d_in[8];
    const float* W0     = (const float*)d_in[9];
    const float* asrc0  = (const float*)d_in[10];
    const float* adst0  = (const float*)d_in[11];
    const float* b0     = (const float*)d_in[12];
    const float* W1     = (const float*)d_in[13];
    const float* asrc1  = (const float*)d_in[14];
    const float* adst1  = (const float*)d_in[15];
    const float* b1     = (const float*)d_in[16];
    const float* ln_g   = (const float*)d_in[17];
    const float* ln_b   = (const float*)d_in[18];

    const int N = in_sizes[0] / 128;
    const int E = in_sizes[2] / 2;
    const int* esrc = ei;
    const int* edst = ei + E;

    const int NB   = (N >> 8) + 1;
    const int NBLK = (E + TILE - 1) / TILE;

    auto alignup = [](size_t v) { return (v + 255) & ~(size_t)255; };
    char* w = (char*)d_ws;
    int* S      = (int*)w; w += alignup((size_t)NB * NBLK * 4);
    int* bsum   = (int*)w; w += alignup(4096);
    int* part   = (int*)w; w += alignup((size_t)E * 4);
    int* offs   = (int*)w; w += alignup((size_t)(N + 1) * 4);
    int* csr    = (int*)w; w += alignup((size_t)E * 4);
    ushort* Sb  = (ushort*)w; w += alignup((size_t)N * 64 * 2);
    ushort* hb  = (ushort*)w; w += alignup((size_t)N * 64 * 2);
    ushort* g0b = (ushort*)w; w += alignup((size_t)N * 64 * 2);
    float2* as2 = (float2*)w; w += alignup((size_t)N * 8);
    float2* ad2 = (float2*)w; w += alignup((size_t)N * 8);
    float* R    = (float*)w; w += alignup(64 * 64 * 4);
    float* cvec = (float*)w; w += alignup(64 * 4);

    // ---- CSR build ----
    const int tot = NB * NBLK;
    const int nbS = (tot + 1023) / 1024;
    k_hist<<<NBLK, TPB, 0, stream>>>(edst, S, E, NB, NBLK);
    k_scan1<<<nbS, TPB, 0, stream>>>(S, bsum, tot);
    k_scan2<<<1, 256, 0, stream>>>(bsum, nbS);
    k_scan3<<<nbS, TPB, 0, stream>>>(S, bsum, tot);
    k_part<<<NBLK, TPB, 0, stream>>>(esrc, edst, S, part, E, NB, NBLK);
    k_csr<<<NB, TPB, 0, stream>>>(part, S, offs, csr, E, N, NB, NBLK);

    k_rinit<<<1, TPB, 0, stream>>>(rho_w, rho_b, W0, R, cvec);

    int gM = (N + 63) / 64;
    // ---- SignNet ----
    k_sign<<<gM, TPB, 0, stream>>>(eig, phi_w1, phi_b1, phi_w2, phi_b2, Sb, N);

    // ---- GAT layer 0: MFMA GEMM (K=128 fp32-x | 64 bf16-S), fused alpha ----
    k_mmfma<128, 64><<<gM, TPB, 0, stream>>>(x, Sb, W0, R, cvec, asrc0, adst0, as2, ad2, hb, N);
    int ga = (N + 3) / 4;
    k_agg<0><<<ga, TPB, 0, stream>>>(offs, csr, hb, as2, ad2, b0, nullptr, nullptr, g0b, N);

    // ---- GAT layer 1: MFMA GEMM (K=64 bf16), fused alpha ----
    k_mmfma<0, 64><<<gM, TPB, 0, stream>>>(nullptr, g0b, nullptr, W1, nullptr, asrc1, adst1, as2, ad2, hb, N);
    k_agg<1><<<ga, TPB, 0, stream>>>(offs, csr, hb, as2, ad2, b1, ln_g, ln_b, d_out, N);

    (void)n_in; (void)ws_size; (void)out_size;
}

// Round 12
// 238.998 us; speedup vs baseline: 2.1751x; 1.1013x over previous
//
#include <hip/hip_runtime.h>
#include <cstdint>
#include <cstddef>
#include <cstring>

#define TPB 256
#define TILE 8192

typedef float f32x2 __attribute__((ext_vector_type(2)));
typedef float f32x4 __attribute__((ext_vector_type(4)));
typedef short short8_t __attribute__((ext_vector_type(8)));

__device__ __forceinline__ ushort f2b(float f) {
    union { float f; uint32_t u; } v; v.f = f;
    uint32_t r = (v.u + 0x7FFFu + ((v.u >> 16) & 1u)) >> 16;
    return (ushort)r;
}
__device__ __forceinline__ float b2f(ushort h) {
    union { uint32_t u; float f; } v; v.u = ((uint32_t)h) << 16;
    return v.f;
}
__device__ __forceinline__ float b2f_lo(uint32_t u) {
    union { uint32_t u; float f; } v; v.u = u << 16;
    return v.f;
}
__device__ __forceinline__ float b2f_hi(uint32_t u) {
    union { uint32_t u; float f; } v; v.u = u & 0xFFFF0000u;
    return v.f;
}
__device__ __forceinline__ float f16lo2f(uint32_t u) {
    union { ushort s; _Float16 h; } v; v.s = (ushort)u;
    return (float)v.h;
}
__device__ __forceinline__ uint32_t pack_f16x2(float p0, float p1) {
    auto hp = __builtin_amdgcn_cvt_pkrtz(p0, p1);
    uint32_t pk;
    __builtin_memcpy(&pk, &hp, 4);
    return pk;
}

// ================ CSR build: LDS-histogram radix partition ================

__global__ __launch_bounds__(TPB) void k_hist(const int* __restrict__ dst, int* __restrict__ hist,
                                              int E, int NB, int NBLK) {
    __shared__ int hc[512];
    const int t = threadIdx.x, blk = blockIdx.x;
    for (int b = t; b < NB; b += TPB) hc[b] = 0;
    __syncthreads();
    const int e0 = blk * TILE;
    for (int i = t; i < TILE; i += TPB) {
        int e = e0 + i;
        if (e < E) atomicAdd(&hc[dst[e] >> 8], 1);
    }
    __syncthreads();
    for (int b = t; b < NB; b += TPB) hist[b * NBLK + blk] = hc[b];
}

__global__ __launch_bounds__(TPB) void k_scan1(const int* __restrict__ a, int* __restrict__ bsum, int total) {
    __shared__ int sh[TPB];
    int base = blockIdx.x * 1024;
    int s = 0;
#pragma unroll
    for (int j = 0; j < 4; ++j) {
        int idx = base + threadIdx.x * 4 + j;
        if (idx < total) s += a[idx];
    }
    sh[threadIdx.x] = s;
    __syncthreads();
    for (int off = 128; off > 0; off >>= 1) {
        if (threadIdx.x < off) sh[threadIdx.x] += sh[threadIdx.x + off];
        __syncthreads();
    }
    if (threadIdx.x == 0) bsum[blockIdx.x] = sh[0];
}

__global__ void k_scan2(int* __restrict__ bsum, int nb) {
    __shared__ int sh[256];
    int t = threadIdx.x;
    int v = (t < nb) ? bsum[t] : 0;
    sh[t] = v;
    __syncthreads();
    for (int off = 1; off < 256; off <<= 1) {
        int u = (t >= off) ? sh[t - off] : 0;
        __syncthreads();
        sh[t] += u;
        __syncthreads();
    }
    if (t < nb) bsum[t] = sh[t] - v;
}

__global__ __launch_bounds__(TPB) void k_scan3(int* __restrict__ a, const int* __restrict__ bsum, int total) {
    __shared__ int sh[TPB];
    int base = blockIdx.x * 1024;
    int v[4];
    int s = 0;
#pragma unroll
    for (int j = 0; j < 4; ++j) {
        int idx = base + threadIdx.x * 4 + j;
        v[j] = (idx < total) ? a[idx] : 0;
        s += v[j];
    }
    sh[threadIdx.x] = s;
    __syncthreads();
    for (int off = 1; off < TPB; off <<= 1) {
        int t = (threadIdx.x >= off) ? sh[threadIdx.x - off] : 0;
        __syncthreads();
        sh[threadIdx.x] += t;
        __syncthreads();
    }
    int pre = bsum[blockIdx.x] + sh[threadIdx.x] - s;
#pragma unroll
    for (int j = 0; j < 4; ++j) {
        int idx = base + threadIdx.x * 4 + j;
        if (idx < total) { a[idx] = pre; pre += v[j]; }
    }
}

__global__ __launch_bounds__(TPB) void k_part(const int* __restrict__ src, const int* __restrict__ dst,
                                              const int* __restrict__ S, int* __restrict__ part,
                                              int E, int NB, int NBLK) {
    __shared__ int hbase[512];
    __shared__ int hcur[512];
    const int t = threadIdx.x, blk = blockIdx.x;
    for (int b = t; b < NB; b += TPB) { hbase[b] = S[b * NBLK + blk]; hcur[b] = 0; }
    __syncthreads();
    const int e0 = blk * TILE;
    for (int i = t; i < TILE; i += TPB) {
        int e = e0 + i;
        if (e < E) {
            int d = dst[e];
            int bu = d >> 8;
            int r = atomicAdd(&hcur[bu], 1);
            part[hbase[bu] + r] = (src[e] << 8) | (d & 255);
        }
    }
}

__global__ __launch_bounds__(TPB) void k_csr(const int* __restrict__ part, const int* __restrict__ S,
                                             int* __restrict__ offs, int* __restrict__ csr,
                                             int E, int N, int NB, int NBLK) {
    __shared__ int cnt[256];
    __shared__ int pre[256];
    const int t = threadIdx.x, b = blockIdx.x;
    const int bstart = S[b * NBLK];
    const int bend = (b + 1 < NB) ? S[(b + 1) * NBLK] : E;
    cnt[t] = 0;
    __syncthreads();
    for (int e = bstart + t; e < bend; e += TPB) atomicAdd(&cnt[part[e] & 255], 1);
    __syncthreads();
    int c = cnt[t];
    pre[t] = c;
    __syncthreads();
    for (int off = 1; off < 256; off <<= 1) {
        int u = (t >= off) ? pre[t - off] : 0;
        __syncthreads();
        pre[t] += u;
        __syncthreads();
    }
    int ex = pre[t] - c;
    int node = b * 256 + t;
    if (node <= N) offs[node] = bstart + ex;
    pre[t] = ex;
    cnt[t] = 0;
    __syncthreads();
    for (int e = bstart + t; e < bend; e += TPB) {
        int pk = part[e];
        int local = pk & 255;
        int r = atomicAdd(&cnt[local], 1);
        csr[bstart + pre[local] + r] = pk >> 8;
    }
}

// ---------------- R = rho_w @ W0_pe ; cvec = rho_b @ W0_pe ----------------

__global__ __launch_bounds__(TPB) void k_rinit(const float* __restrict__ rho_w, const float* __restrict__ rho_b,
                                               const float* __restrict__ W0, float* __restrict__ R,
                                               float* __restrict__ cvec) {
    const float* Wpe = W0 + 128 * 64;
    int tid = threadIdx.x;
    for (int idx = tid; idx < 64 * 64; idx += TPB) {
        int r = idx >> 6, cc = idx & 63;
        float s = 0.f;
#pragma unroll
        for (int k = 0; k < 32; ++k) s = fmaf(rho_w[r * 32 + k], Wpe[k * 64 + cc], s);
        R[idx] = s;
    }
    if (tid < 64) {
        float s = 0.f;
#pragma unroll
        for (int k = 0; k < 32; ++k) s = fmaf(rho_b[k], Wpe[k * 64 + tid], s);
        cvec[tid] = s;
    }
}

// ---------------- fused SignNet: phi1 VALU + phi2 dual-MFMA ----------------
// S = relu(P@w2+b2) + relu(Q@w2+b2), P/Q = relu(+-eig@w1+b1), all bf16 operands.
// Ap/Aq in LDS [row][hid] (pad 8); Wt = w2^T [col][k]; C/D layout per m89.

__global__ __launch_bounds__(TPB) void k_sign(const float* __restrict__ eig,
                                              const float* __restrict__ w1, const float* __restrict__ b1,
                                              const float* __restrict__ w2, const float* __restrict__ b2,
                                              ushort* __restrict__ S, int M) {
    constexpr int K = 64, KP = K + 8;
    __shared__ __align__(16) ushort Ap[64 * KP];
    __shared__ __align__(16) ushort Aq[64 * KP];
    __shared__ __align__(16) ushort Wt[64 * KP];
    __shared__ float w1s[512];
    __shared__ float b1s[64];
    const int tid = threadIdx.x;
    const int row0 = blockIdx.x * 64;

    for (int i = tid; i < 512; i += TPB) w1s[i] = w1[i];
    if (tid < 64) b1s[tid] = b1[tid];
    // Wt[c*KP + k] = bf16(w2[k][c])
    for (int idx = tid; idx < K * 16; idx += TPB) {
        int k = idx >> 4;
        int c4 = (idx & 15) * 4;
        float4 v = *(const float4*)(w2 + (size_t)k * 64 + c4);
        Wt[(c4 + 0) * KP + k] = f2b(v.x);
        Wt[(c4 + 1) * KP + k] = f2b(v.y);
        Wt[(c4 + 2) * KP + k] = f2b(v.z);
        Wt[(c4 + 3) * KP + k] = f2b(v.w);
    }
    __syncthreads();
    // phi1: thread (r = tid>>2, csub = tid&3) computes cols csub*16..+15 of row r
    {
        int r = tid >> 2, csub = tid & 3;
        int row = row0 + r; int rowc = row < M ? row : M - 1;
        float4 e0 = *(const float4*)(eig + (size_t)rowc * 8);
        float4 e1 = *(const float4*)(eig + (size_t)rowc * 8 + 4);
        float ev[8] = {e0.x, e0.y, e0.z, e0.w, e1.x, e1.y, e1.z, e1.w};
#pragma unroll
        for (int c0 = 0; c0 < 16; ++c0) {
            int c = csub * 16 + c0;
            float t = 0.f;
#pragma unroll
            for (int k = 0; k < 8; ++k) t = fmaf(ev[k], w1s[k * 64 + c], t);
            float bb = b1s[c];
            Ap[r * KP + c] = f2b(fmaxf(t + bb, 0.f));
            Aq[r * KP + c] = f2b(fmaxf(bb - t, 0.f));
        }
    }
    __syncthreads();

    const int w = tid >> 6, lane = tid & 63;
    const int lr = lane & 15, kg = lane >> 4;
    f32x4 ap0 = {0.f, 0.f, 0.f, 0.f}, ap1 = ap0, ap2 = ap0, ap3 = ap0;
    f32x4 aq0 = ap0, aq1 = ap0, aq2 = ap0, aq3 = ap0;
    const ushort* prow = &Ap[(w * 16 + lr) * KP + kg * 8];
    const ushort* qrow = &Aq[(w * 16 + lr) * KP + kg * 8];
    const ushort* bp0 = &Wt[(0 + lr) * KP + kg * 8];
    const ushort* bp1 = &Wt[(16 + lr) * KP + kg * 8];
    const ushort* bp2 = &Wt[(32 + lr) * KP + kg * 8];
    const ushort* bp3 = &Wt[(48 + lr) * KP + kg * 8];
#pragma unroll
    for (int k0 = 0; k0 < K; k0 += 32) {
        short8_t pf = *(const short8_t*)(prow + k0);
        short8_t qf = *(const short8_t*)(qrow + k0);
        short8_t b0 = *(const short8_t*)(bp0 + k0);
        short8_t b1f = *(const short8_t*)(bp1 + k0);
        short8_t b2f_ = *(const short8_t*)(bp2 + k0);
        short8_t b3 = *(const short8_t*)(bp3 + k0);
        ap0 = __builtin_amdgcn_mfma_f32_16x16x32_bf16(pf, b0, ap0, 0, 0, 0);
        aq0 = __builtin_amdgcn_mfma_f32_16x16x32_bf16(qf, b0, aq0, 0, 0, 0);
        ap1 = __builtin_amdgcn_mfma_f32_16x16x32_bf16(pf, b1f, ap1, 0, 0, 0);
        aq1 = __builtin_amdgcn_mfma_f32_16x16x32_bf16(qf, b1f, aq1, 0, 0, 0);
        ap2 = __builtin_amdgcn_mfma_f32_16x16x32_bf16(pf, b2f_, ap2, 0, 0, 0);
        aq2 = __builtin_amdgcn_mfma_f32_16x16x32_bf16(qf, b2f_, aq2, 0, 0, 0);
        ap3 = __builtin_amdgcn_mfma_f32_16x16x32_bf16(pf, b3, ap3, 0, 0, 0);
        aq3 = __builtin_amdgcn_mfma_f32_16x16x32_bf16(qf, b3, aq3, 0, 0, 0);
    }

    float bb0 = b2[lr], bb1 = b2[16 + lr], bb2 = b2[32 + lr], bb3 = b2[48 + lr];
#pragma unroll
    for (int i = 0; i < 4; ++i) {
        int row = row0 + w * 16 + kg * 4 + i;
        if (row >= M) continue;
        float v0 = fmaxf(ap0[i] + bb0, 0.f) + fmaxf(aq0[i] + bb0, 0.f);
        float v1 = fmaxf(ap1[i] + bb1, 0.f) + fmaxf(aq1[i] + bb1, 0.f);
        float v2 = fmaxf(ap2[i] + bb2, 0.f) + fmaxf(aq2[i] + bb2, 0.f);
        float v3 = fmaxf(ap3[i] + bb3, 0.f) + fmaxf(aq3[i] + bb3, 0.f);
        ushort* orow = S + (size_t)row * 64 + lr;
        orow[0]  = f2b(v0);
        orow[16] = f2b(v1);
        orow[32] = f2b(v2);
        orow[48] = f2b(v3);
    }
}

// ---------------- MFMA GEMM + fused alpha (unchanged from round 11) ----------------

template <int K1, int K2>
__global__ __launch_bounds__(TPB) void k_mmfma(const float* __restrict__ A1,
                                               const ushort* __restrict__ A2,
                                               const float* __restrict__ Wa, const float* __restrict__ Wb,
                                               const float* __restrict__ bias,
                                               const float* __restrict__ a_s, const float* __restrict__ a_d,
                                               float2* __restrict__ as2, float2* __restrict__ ad2,
                                               ushort* __restrict__ out, int M) {
    constexpr int K = K1 + K2;
    constexpr int KP = K + 8;
    __shared__ __align__(16) ushort Ab[64 * KP];
    __shared__ __align__(16) ushort Wt[64 * KP];
    const int tid = threadIdx.x;
    const int row0 = blockIdx.x * 64;

    if constexpr (K1 > 0) {
        for (int idx = tid; idx < 64 * K1 / 4; idx += TPB) {
            int r = idx / (K1 / 4);
            int c4 = (idx % (K1 / 4)) * 4;
            int row = row0 + r; int rowc = row < M ? row : M - 1;
            float4 v = *(const float4*)(A1 + (size_t)rowc * K1 + c4);
            Ab[r * KP + c4 + 0] = f2b(v.x);
            Ab[r * KP + c4 + 1] = f2b(v.y);
            Ab[r * KP + c4 + 2] = f2b(v.z);
            Ab[r * KP + c4 + 3] = f2b(v.w);
        }
    }
    if constexpr (K2 > 0) {
        for (int idx = tid; idx < 64 * K2 / 4; idx += TPB) {
            int r = idx / (K2 / 4);
            int c4 = (idx % (K2 / 4)) * 4;
            int row = row0 + r; int rowc = row < M ? row : M - 1;
            ushort4 u = *(const ushort4*)(A2 + (size_t)rowc * K2 + c4);
            Ab[r * KP + K1 + c4 + 0] = u.x;
            Ab[r * KP + K1 + c4 + 1] = u.y;
            Ab[r * KP + K1 + c4 + 2] = u.z;
            Ab[r * KP + K1 + c4 + 3] = u.w;
        }
    }
    for (int idx = tid; idx < K * 16; idx += TPB) {
        int k = idx / 16;
        int c4 = (idx % 16) * 4;
        const float* Wrow = (K1 > 0 && k < K1) ? (Wa + (size_t)k * 64) : (Wb + (size_t)(k - K1) * 64);
        float4 v = *(const float4*)(Wrow + c4);
        Wt[(c4 + 0) * KP + k] = f2b(v.x);
        Wt[(c4 + 1) * KP + k] = f2b(v.y);
        Wt[(c4 + 2) * KP + k] = f2b(v.z);
        Wt[(c4 + 3) * KP + k] = f2b(v.w);
    }
    __syncthreads();

    const int w = tid >> 6, lane = tid & 63;
    const int lr = lane & 15, kg = lane >> 4;
    f32x4 acc0 = {0.f, 0.f, 0.f, 0.f}, acc1 = acc0, acc2 = acc0, acc3 = acc0;
    const ushort* arow = &Ab[(w * 16 + lr) * KP + kg * 8];
    const ushort* bp0 = &Wt[(0 + lr) * KP + kg * 8];
    const ushort* bp1 = &Wt[(16 + lr) * KP + kg * 8];
    const ushort* bp2 = &Wt[(32 + lr) * KP + kg * 8];
    const ushort* bp3 = &Wt[(48 + lr) * KP + kg * 8];
#pragma unroll
    for (int k0 = 0; k0 < K; k0 += 32) {
        short8_t af = *(const short8_t*)(arow + k0);
        short8_t b0 = *(const short8_t*)(bp0 + k0);
        short8_t b1 = *(const short8_t*)(bp1 + k0);
        short8_t b2 = *(const short8_t*)(bp2 + k0);
        short8_t b3 = *(const short8_t*)(bp3 + k0);
        acc0 = __builtin_amdgcn_mfma_f32_16x16x32_bf16(af, b0, acc0, 0, 0, 0);
        acc1 = __builtin_amdgcn_mfma_f32_16x16x32_bf16(af, b1, acc1, 0, 0, 0);
        acc2 = __builtin_amdgcn_mfma_f32_16x16x32_bf16(af, b2, acc2, 0, 0, 0);
        acc3 = __builtin_amdgcn_mfma_f32_16x16x32_bf16(af, b3, acc3, 0, 0, 0);
    }

    float asr0 = a_s[lr], asr1 = a_s[16 + lr], asr2 = a_s[32 + lr], asr3 = a_s[48 + lr];
    float adr0 = a_d[lr], adr1 = a_d[16 + lr], adr2 = a_d[32 + lr], adr3 = a_d[48 + lr];
    float bb0 = 0.f, bb1 = 0.f, bb2 = 0.f, bb3 = 0.f;
    if (bias) { bb0 = bias[lr]; bb1 = bias[16 + lr]; bb2 = bias[32 + lr]; bb3 = bias[48 + lr]; }

#pragma unroll
    for (int i = 0; i < 4; ++i) {
        int row = row0 + w * 16 + kg * 4 + i;
        float v0 = acc0[i] + bb0;
        float v1 = acc1[i] + bb1;
        float v2 = acc2[i] + bb2;
        float v3 = acc3[i] + bb3;
        float sh0 = fmaf(v0, asr0, v1 * asr1);
        float sh1 = fmaf(v2, asr2, v3 * asr3);
        float dh0 = fmaf(v0, adr0, v1 * adr1);
        float dh1 = fmaf(v2, adr2, v3 * adr3);
#pragma unroll
        for (int m = 1; m <= 8; m <<= 1) {
            sh0 += __shfl_xor(sh0, m);
            sh1 += __shfl_xor(sh1, m);
            dh0 += __shfl_xor(dh0, m);
            dh1 += __shfl_xor(dh1, m);
        }
        if (row < M) {
            ushort* orow = out + (size_t)row * 64 + lr;
            orow[0]  = f2b(v0);
            orow[16] = f2b(v1);
            orow[32] = f2b(v2);
            orow[48] = f2b(v3);
            if (lr == 0) {
                as2[row] = make_float2(sh0, sh1);
                ad2[row] = make_float2(dh0, dh1);
            }
        }
    }
}

// ---------------- GAT aggregation (unchanged) ----------------

template <int DO_LN>
__global__ __launch_bounds__(TPB) void k_agg(const int* __restrict__ offs, const int* __restrict__ csr_src,
                                             const ushort* __restrict__ hb,
                                             const float2* __restrict__ as2,
                                             const float2* __restrict__ ad2,
                                             const float* __restrict__ bias,
                                             const float* __restrict__ ln_g,
                                             const float* __restrict__ ln_b,
                                             void* __restrict__ out_v, int M) {
    __shared__ uint2 ep[4][64];
    int w = (blockIdx.x * blockDim.x + threadIdx.x) >> 6;
    int lane = threadIdx.x & 63;
    int wl = threadIdx.x >> 6;
    if (w >= M) return;
    const int sub = lane & 15;
    const int grp = lane >> 4;
    const int c0 = sub * 4;
    const int head = sub >> 3;
    const int hshift = head << 4;

    float2 adv = ad2[w];
    int beg = offs[w], end = offs[w + 1];
    f32x2 acc01 = {0.f, 0.f}, acc23 = {0.f, 0.f};
    float qs = 0.f;

    for (int base = beg; base < end; base += 64) {
        int nk = end - base;
        if (nk > 64) nk = 64;
        int sidx = csr_src[base + (lane < nk ? lane : 0)];
        float2 av = as2[sidx];
        float e0 = av.x + adv.x; e0 = e0 > 0.f ? e0 : 0.2f * e0;
        float e1 = av.y + adv.y; e1 = e1 > 0.f ? e1 : 0.2f * e1;
        float p0 = __expf(e0), p1 = __expf(e1);
        if (lane >= nk) { p0 = 0.f; p1 = 0.f; }
        ep[wl][lane] = make_uint2((uint32_t)sidx, pack_f16x2(p0, p1));

        int j = 0;
        for (; j + 8 <= nk; j += 8) {
            uint2 eA = ep[wl][j + grp];
            uint2 eB = ep[wl][j + 4 + grp];
            uint2 uA = *(const uint2*)(hb + ((uint32_t)eA.x << 6) + c0);
            uint2 uB = *(const uint2*)(hb + ((uint32_t)eB.x << 6) + c0);
            float qA = f16lo2f(eA.y >> hshift);
            float qB = f16lo2f(eB.y >> hshift);
            qs += qA + qB;
            f32x2 hA01 = {b2f_lo(uA.x), b2f_hi(uA.x)};
            f32x2 hA23 = {b2f_lo(uA.y), b2f_hi(uA.y)};
            f32x2 hB01 = {b2f_lo(uB.x), b2f_hi(uB.x)};
            f32x2 hB23 = {b2f_lo(uB.y), b2f_hi(uB.y)};
            acc01 += qA * hA01;
            acc23 += qA * hA23;
            acc01 += qB * hB01;
            acc23 += qB * hB23;
        }
        for (; j < nk; j += 4) {
            int src = j + grp;
            if (src > 63) src = 63;
            uint2 e = ep[wl][src];
            uint2 u = *(const uint2*)(hb + ((uint32_t)e.x << 6) + c0);
            float q = f16lo2f(e.y >> hshift);
            qs += q;
            f32x2 h01 = {b2f_lo(u.x), b2f_hi(u.x)};
            f32x2 h23 = {b2f_lo(u.y), b2f_hi(u.y)};
            acc01 += q * h01;
            acc23 += q * h23;
        }
    }
    float a0 = acc01.x, a1 = acc01.y, a2 = acc23.x, a3 = acc23.y;
    a0 += __shfl_xor(a0, 16); a0 += __shfl_xor(a0, 32);
    a1 += __shfl_xor(a1, 16); a1 += __shfl_xor(a1, 32);
    a2 += __shfl_xor(a2, 16); a2 += __shfl_xor(a2, 32);
    a3 += __shfl_xor(a3, 16); a3 += __shfl_xor(a3, 32);
    qs += __shfl_xor(qs, 16); qs += __shfl_xor(qs, 32);

    float inv = 1.f / (qs + 1e-16f);
    float4 bb = *(const float4*)(bias + c0);
    float o0 = fmaf(a0, inv, bb.x);
    float o1 = fmaf(a1, inv, bb.y);
    float o2 = fmaf(a2, inv, bb.z);
    float o3 = fmaf(a3, inv, bb.w);
    o0 = o0 > 0.f ? o0 : expm1f(o0);
    o1 = o1 > 0.f ? o1 : expm1f(o1);
    o2 = o2 > 0.f ? o2 : expm1f(o2);
    o3 = o3 > 0.f ? o3 : expm1f(o3);

    if (DO_LN) {
        float mu = o0 + o1 + o2 + o3;
#pragma unroll
        for (int m = 1; m <= 8; m <<= 1) mu += __shfl_xor(mu, m);
        mu *= (1.f / 64.f);
        float dv = (o0 - mu) * (o0 - mu) + (o1 - mu) * (o1 - mu)
                 + (o2 - mu) * (o2 - mu) + (o3 - mu) * (o3 - mu);
#pragma unroll
        for (int m = 1; m <= 8; m <<= 1) dv += __shfl_xor(dv, m);
        dv *= (1.f / 64.f);
        float rs = rsqrtf(dv + 1e-5f);
        float4 g = *(const float4*)(ln_g + c0);
        float4 b = *(const float4*)(ln_b + c0);
        o0 = (o0 - mu) * rs * g.x + b.x;
        o1 = (o1 - mu) * rs * g.y + b.y;
        o2 = (o2 - mu) * rs * g.z + b.z;
        o3 = (o3 - mu) * rs * g.w + b.w;
        if (lane < 16) {
            float4* out = (float4*)out_v;
            out[(size_t)w * 16 + sub] = make_float4(o0, o1, o2, o3);
        }
    } else {
        if (lane < 16) {
            uint2 pk2;
            pk2.x = (uint32_t)f2b(o0) | ((uint32_t)f2b(o1) << 16);
            pk2.y = (uint32_t)f2b(o2) | ((uint32_t)f2b(o3) << 16);
            uint2* out = (uint2*)out_v;
            out[(size_t)w * 16 + sub] = pk2;
        }
    }
}

// ---------------- launcher ----------------

extern "C" void kernel_launch(void* const* d_in, const int* in_sizes, int n_in,
                              void* d_out, int out_size, void* d_ws, size_t ws_size,
                              hipStream_t stream) {
    const float* x      = (const float*)d_in[0];
    const float* eig    = (const float*)d_in[1];
    const int*   ei     = (const int*)d_in[2];
    const float* phi_w1 = (const float*)d_in[3];
    const float* phi_b1 = (const float*)d_in[4];
    const float* phi_w2 = (const float*)d_in[5];
    const float* phi_b2 = (const float*)d_in[6];
    const float* rho_w  = (const float*)d_in[7];
    const float* rho_b  = (const float*)d_in[8];
    const float* W0     = (const float*)d_in[9];
    const float* asrc0  = (const float*)d_in[10];
    const float* adst0  = (const float*)d_in[11];
    const float* b0     = (const float*)d_in[12];
    const float* W1     = (const float*)d_in[13];
    const float* asrc1  = (const float*)d_in[14];
    const float* adst1  = (const float*)d_in[15];
    const float* b1     = (const float*)d_in[16];
    const float* ln_g   = (const float*)d_in[17];
    const float* ln_b   = (const float*)d_in[18];

    const int N = in_sizes[0] / 128;
    const int E = in_sizes[2] / 2;
    const int* esrc = ei;
    const int* edst = ei + E;

    const int NB   = (N >> 8) + 1;
    const int NBLK = (E + TILE - 1) / TILE;

    auto alignup = [](size_t v) { return (v + 255) & ~(size_t)255; };
    char* w = (char*)d_ws;
    int* S      = (int*)w; w += alignup((size_t)NB * NBLK * 4);
    int* bsum   = (int*)w; w += alignup(4096);
    int* part   = (int*)w; w += alignup((size_t)E * 4);
    int* offs   = (int*)w; w += alignup((size_t)(N + 1) * 4);
    int* csr    = (int*)w; w += alignup((size_t)E * 4);
    ushort* Sb  = (ushort*)w; w += alignup((size_t)N * 64 * 2);
    ushort* hb  = (ushort*)w; w += alignup((size_t)N * 64 * 2);
    ushort* g0b = (ushort*)w; w += alignup((size_t)N * 64 * 2);
    float2* as2 = (float2*)w; w += alignup((size_t)N * 8);
    float2* ad2 = (float2*)w; w += alignup((size_t)N * 8);
    float* R    = (float*)w; w += alignup(64 * 64 * 4);
    float* cvec = (float*)w; w += alignup(64 * 4);

    // ---- CSR build ----
    const int tot = NB * NBLK;
    const int nbS = (tot + 1023) / 1024;
    k_hist<<<NBLK, TPB, 0, stream>>>(edst, S, E, NB, NBLK);
    k_scan1<<<nbS, TPB, 0, stream>>>(S, bsum, tot);
    k_scan2<<<1, 256, 0, stream>>>(bsum, nbS);
    k_scan3<<<nbS, TPB, 0, stream>>>(S, bsum, tot);
    k_part<<<NBLK, TPB, 0, stream>>>(esrc, edst, S, part, E, NB, NBLK);
    k_csr<<<NB, TPB, 0, stream>>>(part, S, offs, csr, E, N, NB, NBLK);

    k_rinit<<<1, TPB, 0, stream>>>(rho_w, rho_b, W0, R, cvec);

    int gM = (N + 63) / 64;
    // ---- SignNet (phi1 VALU + phi2 MFMA) ----
    k_sign<<<gM, TPB, 0, stream>>>(eig, phi_w1, phi_b1, phi_w2, phi_b2, Sb, N);

    // ---- GAT layer 0: MFMA GEMM (K=128 fp32-x | 64 bf16-S), fused alpha ----
    k_mmfma<128, 64><<<gM, TPB, 0, stream>>>(x, Sb, W0, R, cvec, asrc0, adst0, as2, ad2, hb, N);
    int ga = (N + 3) / 4;
    k_agg<0><<<ga, TPB, 0, stream>>>(offs, csr, hb, as2, ad2, b0, nullptr, nullptr, g0b, N);

    // ---- GAT layer 1: MFMA GEMM (K=64 bf16), fused alpha ----
    k_mmfma<0, 64><<<gM, TPB, 0, stream>>>(nullptr, g0b, nullptr, W1, nullptr, asrc1, adst1, as2, ad2, hb, N);
    k_agg<1><<<ga, TPB, 0, stream>>>(offs, csr, hb, as2, ad2, b1, ln_g, ln_b, d_out, N);

    (void)n_in; (void)ws_size; (void)out_size;
}

// Round 13
// 235.352 us; speedup vs baseline: 2.2088x; 1.0155x over previous
//
#include <hip/hip_runtime.h>
#include <cstdint>
#include <cstddef>
#include <cstring>

#define TPB 256
#define TILE 8192

typedef float f32x2 __attribute__((ext_vector_type(2)));
typedef float f32x4 __attribute__((ext_vector_type(4)));
typedef short short8_t __attribute__((ext_vector_type(8)));

__device__ __forceinline__ ushort f2b(float f) {
    union { float f; uint32_t u; } v; v.f = f;
    uint32_t r = (v.u + 0x7FFFu + ((v.u >> 16) & 1u)) >> 16;
    return (ushort)r;
}
__device__ __forceinline__ float b2f(ushort h) {
    union { uint32_t u; float f; } v; v.u = ((uint32_t)h) << 16;
    return v.f;
}
__device__ __forceinline__ float b2f_lo(uint32_t u) {
    union { uint32_t u; float f; } v; v.u = u << 16;
    return v.f;
}
__device__ __forceinline__ float b2f_hi(uint32_t u) {
    union { uint32_t u; float f; } v; v.u = u & 0xFFFF0000u;
    return v.f;
}
__device__ __forceinline__ float f16lo2f(uint32_t u) {
    union { ushort s; _Float16 h; } v; v.s = (ushort)u;
    return (float)v.h;
}
__device__ __forceinline__ uint32_t pack_f16x2(float p0, float p1) {
    auto hp = __builtin_amdgcn_cvt_pkrtz(p0, p1);
    uint32_t pk;
    __builtin_memcpy(&pk, &hp, 4);
    return pk;
}

// ================ CSR build: LDS-histogram radix partition ================

__global__ __launch_bounds__(TPB) void k_hist(const int* __restrict__ dst, int* __restrict__ hist,
                                              int E, int NB, int NBLK) {
    __shared__ int hc[512];
    const int t = threadIdx.x, blk = blockIdx.x;
    for (int b = t; b < NB; b += TPB) hc[b] = 0;
    __syncthreads();
    const int e0 = blk * TILE;
    for (int i = t; i < TILE; i += TPB) {
        int e = e0 + i;
        if (e < E) atomicAdd(&hc[dst[e] >> 8], 1);
    }
    __syncthreads();
    for (int b = t; b < NB; b += TPB) hist[b * NBLK + blk] = hc[b];
}

__global__ __launch_bounds__(TPB) void k_scan1(const int* __restrict__ a, int* __restrict__ bsum, int total) {
    __shared__ int sh[TPB];
    int base = blockIdx.x * 1024;
    int s = 0;
#pragma unroll
    for (int j = 0; j < 4; ++j) {
        int idx = base + threadIdx.x * 4 + j;
        if (idx < total) s += a[idx];
    }
    sh[threadIdx.x] = s;
    __syncthreads();
    for (int off = 128; off > 0; off >>= 1) {
        if (threadIdx.x < off) sh[threadIdx.x] += sh[threadIdx.x + off];
        __syncthreads();
    }
    if (threadIdx.x == 0) bsum[blockIdx.x] = sh[0];
}

__global__ void k_scan2(int* __restrict__ bsum, int nb) {
    __shared__ int sh[256];
    int t = threadIdx.x;
    int v = (t < nb) ? bsum[t] : 0;
    sh[t] = v;
    __syncthreads();
    for (int off = 1; off < 256; off <<= 1) {
        int u = (t >= off) ? sh[t - off] : 0;
        __syncthreads();
        sh[t] += u;
        __syncthreads();
    }
    if (t < nb) bsum[t] = sh[t] - v;
}

__global__ __launch_bounds__(TPB) void k_scan3(int* __restrict__ a, const int* __restrict__ bsum, int total) {
    __shared__ int sh[TPB];
    int base = blockIdx.x * 1024;
    int v[4];
    int s = 0;
#pragma unroll
    for (int j = 0; j < 4; ++j) {
        int idx = base + threadIdx.x * 4 + j;
        v[j] = (idx < total) ? a[idx] : 0;
        s += v[j];
    }
    sh[threadIdx.x] = s;
    __syncthreads();
    for (int off = 1; off < TPB; off <<= 1) {
        int t = (threadIdx.x >= off) ? sh[threadIdx.x - off] : 0;
        __syncthreads();
        sh[threadIdx.x] += t;
        __syncthreads();
    }
    int pre = bsum[blockIdx.x] + sh[threadIdx.x] - s;
#pragma unroll
    for (int j = 0; j < 4; ++j) {
        int idx = base + threadIdx.x * 4 + j;
        if (idx < total) { a[idx] = pre; pre += v[j]; }
    }
}

__global__ __launch_bounds__(TPB) void k_part(const int* __restrict__ src, const int* __restrict__ dst,
                                              const int* __restrict__ S, int* __restrict__ part,
                                              int E, int NB, int NBLK) {
    __shared__ int hbase[512];
    __shared__ int hcur[512];
    const int t = threadIdx.x, blk = blockIdx.x;
    for (int b = t; b < NB; b += TPB) { hbase[b] = S[b * NBLK + blk]; hcur[b] = 0; }
    __syncthreads();
    const int e0 = blk * TILE;
    for (int i = t; i < TILE; i += TPB) {
        int e = e0 + i;
        if (e < E) {
            int d = dst[e];
            int bu = d >> 8;
            int r = atomicAdd(&hcur[bu], 1);
            part[hbase[bu] + r] = (src[e] << 8) | (d & 255);
        }
    }
}

__global__ __launch_bounds__(TPB) void k_csr(const int* __restrict__ part, const int* __restrict__ S,
                                             int* __restrict__ offs, int* __restrict__ csr,
                                             int E, int N, int NB, int NBLK) {
    __shared__ int cnt[256];
    __shared__ int pre[256];
    const int t = threadIdx.x, b = blockIdx.x;
    const int bstart = S[b * NBLK];
    const int bend = (b + 1 < NB) ? S[(b + 1) * NBLK] : E;
    cnt[t] = 0;
    __syncthreads();
    for (int e = bstart + t; e < bend; e += TPB) atomicAdd(&cnt[part[e] & 255], 1);
    __syncthreads();
    int c = cnt[t];
    pre[t] = c;
    __syncthreads();
    for (int off = 1; off < 256; off <<= 1) {
        int u = (t >= off) ? pre[t - off] : 0;
        __syncthreads();
        pre[t] += u;
        __syncthreads();
    }
    int ex = pre[t] - c;
    int node = b * 256 + t;
    if (node <= N) offs[node] = bstart + ex;
    pre[t] = ex;
    cnt[t] = 0;
    __syncthreads();
    for (int e = bstart + t; e < bend; e += TPB) {
        int pk = part[e];
        int local = pk & 255;
        int r = atomicAdd(&cnt[local], 1);
        csr[bstart + pre[local] + r] = pk >> 8;
    }
}

// ---------------- R = rho_w @ W0_pe ; cvec = rho_b @ W0_pe ----------------

__global__ __launch_bounds__(TPB) void k_rinit(const float* __restrict__ rho_w, const float* __restrict__ rho_b,
                                               const float* __restrict__ W0, float* __restrict__ R,
                                               float* __restrict__ cvec) {
    const float* Wpe = W0 + 128 * 64;
    int tid = threadIdx.x;
    for (int idx = tid; idx < 64 * 64; idx += TPB) {
        int r = idx >> 6, cc = idx & 63;
        float s = 0.f;
#pragma unroll
        for (int k = 0; k < 32; ++k) s = fmaf(rho_w[r * 32 + k], Wpe[k * 64 + cc], s);
        R[idx] = s;
    }
    if (tid < 64) {
        float s = 0.f;
#pragma unroll
        for (int k = 0; k < 32; ++k) s = fmaf(rho_b[k], Wpe[k * 64 + tid], s);
        cvec[tid] = s;
    }
}

// ---------------- fused SignNet: phi1 VALU + phi2 dual-MFMA ----------------

__global__ __launch_bounds__(TPB) void k_sign(const float* __restrict__ eig,
                                              const float* __restrict__ w1, const float* __restrict__ b1,
                                              const float* __restrict__ w2, const float* __restrict__ b2,
                                              ushort* __restrict__ S, int M) {
    constexpr int K = 64, KP = K + 8;
    __shared__ __align__(16) ushort Ap[64 * KP];
    __shared__ __align__(16) ushort Aq[64 * KP];
    __shared__ __align__(16) ushort Wt[64 * KP];
    __shared__ float w1s[512];
    __shared__ float b1s[64];
    const int tid = threadIdx.x;
    const int row0 = blockIdx.x * 64;

    for (int i = tid; i < 512; i += TPB) w1s[i] = w1[i];
    if (tid < 64) b1s[tid] = b1[tid];
    for (int idx = tid; idx < K * 16; idx += TPB) {
        int k = idx >> 4;
        int c4 = (idx & 15) * 4;
        float4 v = *(const float4*)(w2 + (size_t)k * 64 + c4);
        Wt[(c4 + 0) * KP + k] = f2b(v.x);
        Wt[(c4 + 1) * KP + k] = f2b(v.y);
        Wt[(c4 + 2) * KP + k] = f2b(v.z);
        Wt[(c4 + 3) * KP + k] = f2b(v.w);
    }
    __syncthreads();
    {
        int r = tid >> 2, csub = tid & 3;
        int row = row0 + r; int rowc = row < M ? row : M - 1;
        float4 e0 = *(const float4*)(eig + (size_t)rowc * 8);
        float4 e1 = *(const float4*)(eig + (size_t)rowc * 8 + 4);
        float ev[8] = {e0.x, e0.y, e0.z, e0.w, e1.x, e1.y, e1.z, e1.w};
#pragma unroll
        for (int c0 = 0; c0 < 16; ++c0) {
            int c = csub * 16 + c0;
            float t = 0.f;
#pragma unroll
            for (int k = 0; k < 8; ++k) t = fmaf(ev[k], w1s[k * 64 + c], t);
            float bb = b1s[c];
            Ap[r * KP + c] = f2b(fmaxf(t + bb, 0.f));
            Aq[r * KP + c] = f2b(fmaxf(bb - t, 0.f));
        }
    }
    __syncthreads();

    const int w = tid >> 6, lane = tid & 63;
    const int lr = lane & 15, kg = lane >> 4;
    f32x4 ap0 = {0.f, 0.f, 0.f, 0.f}, ap1 = ap0, ap2 = ap0, ap3 = ap0;
    f32x4 aq0 = ap0, aq1 = ap0, aq2 = ap0, aq3 = ap0;
    const ushort* prow = &Ap[(w * 16 + lr) * KP + kg * 8];
    const ushort* qrow = &Aq[(w * 16 + lr) * KP + kg * 8];
    const ushort* bp0 = &Wt[(0 + lr) * KP + kg * 8];
    const ushort* bp1 = &Wt[(16 + lr) * KP + kg * 8];
    const ushort* bp2 = &Wt[(32 + lr) * KP + kg * 8];
    const ushort* bp3 = &Wt[(48 + lr) * KP + kg * 8];
#pragma unroll
    for (int k0 = 0; k0 < K; k0 += 32) {
        short8_t pf = *(const short8_t*)(prow + k0);
        short8_t qf = *(const short8_t*)(qrow + k0);
        short8_t b0 = *(const short8_t*)(bp0 + k0);
        short8_t b1f = *(const short8_t*)(bp1 + k0);
        short8_t b2f_ = *(const short8_t*)(bp2 + k0);
        short8_t b3 = *(const short8_t*)(bp3 + k0);
        ap0 = __builtin_amdgcn_mfma_f32_16x16x32_bf16(pf, b0, ap0, 0, 0, 0);
        aq0 = __builtin_amdgcn_mfma_f32_16x16x32_bf16(qf, b0, aq0, 0, 0, 0);
        ap1 = __builtin_amdgcn_mfma_f32_16x16x32_bf16(pf, b1f, ap1, 0, 0, 0);
        aq1 = __builtin_amdgcn_mfma_f32_16x16x32_bf16(qf, b1f, aq1, 0, 0, 0);
        ap2 = __builtin_amdgcn_mfma_f32_16x16x32_bf16(pf, b2f_, ap2, 0, 0, 0);
        aq2 = __builtin_amdgcn_mfma_f32_16x16x32_bf16(qf, b2f_, aq2, 0, 0, 0);
        ap3 = __builtin_amdgcn_mfma_f32_16x16x32_bf16(pf, b3, ap3, 0, 0, 0);
        aq3 = __builtin_amdgcn_mfma_f32_16x16x32_bf16(qf, b3, aq3, 0, 0, 0);
    }

    float bb0 = b2[lr], bb1 = b2[16 + lr], bb2 = b2[32 + lr], bb3 = b2[48 + lr];
#pragma unroll
    for (int i = 0; i < 4; ++i) {
        int row = row0 + w * 16 + kg * 4 + i;
        if (row >= M) continue;
        float v0 = fmaxf(ap0[i] + bb0, 0.f) + fmaxf(aq0[i] + bb0, 0.f);
        float v1 = fmaxf(ap1[i] + bb1, 0.f) + fmaxf(aq1[i] + bb1, 0.f);
        float v2 = fmaxf(ap2[i] + bb2, 0.f) + fmaxf(aq2[i] + bb2, 0.f);
        float v3 = fmaxf(ap3[i] + bb3, 0.f) + fmaxf(aq3[i] + bb3, 0.f);
        ushort* orow = S + (size_t)row * 64 + lr;
        orow[0]  = f2b(v0);
        orow[16] = f2b(v1);
        orow[32] = f2b(v2);
        orow[48] = f2b(v3);
    }
}

// ---------------- MFMA GEMM + fused alpha ----------------

template <int K1, int K2>
__global__ __launch_bounds__(TPB) void k_mmfma(const float* __restrict__ A1,
                                               const ushort* __restrict__ A2,
                                               const float* __restrict__ Wa, const float* __restrict__ Wb,
                                               const float* __restrict__ bias,
                                               const float* __restrict__ a_s, const float* __restrict__ a_d,
                                               float2* __restrict__ as2, float2* __restrict__ ad2,
                                               ushort* __restrict__ out, int M) {
    constexpr int K = K1 + K2;
    constexpr int KP = K + 8;
    __shared__ __align__(16) ushort Ab[64 * KP];
    __shared__ __align__(16) ushort Wt[64 * KP];
    const int tid = threadIdx.x;
    const int row0 = blockIdx.x * 64;

    if constexpr (K1 > 0) {
        for (int idx = tid; idx < 64 * K1 / 4; idx += TPB) {
            int r = idx / (K1 / 4);
            int c4 = (idx % (K1 / 4)) * 4;
            int row = row0 + r; int rowc = row < M ? row : M - 1;
            float4 v = *(const float4*)(A1 + (size_t)rowc * K1 + c4);
            Ab[r * KP + c4 + 0] = f2b(v.x);
            Ab[r * KP + c4 + 1] = f2b(v.y);
            Ab[r * KP + c4 + 2] = f2b(v.z);
            Ab[r * KP + c4 + 3] = f2b(v.w);
        }
    }
    if constexpr (K2 > 0) {
        for (int idx = tid; idx < 64 * K2 / 4; idx += TPB) {
            int r = idx / (K2 / 4);
            int c4 = (idx % (K2 / 4)) * 4;
            int row = row0 + r; int rowc = row < M ? row : M - 1;
            ushort4 u = *(const ushort4*)(A2 + (size_t)rowc * K2 + c4);
            Ab[r * KP + K1 + c4 + 0] = u.x;
            Ab[r * KP + K1 + c4 + 1] = u.y;
            Ab[r * KP + K1 + c4 + 2] = u.z;
            Ab[r * KP + K1 + c4 + 3] = u.w;
        }
    }
    for (int idx = tid; idx < K * 16; idx += TPB) {
        int k = idx / 16;
        int c4 = (idx % 16) * 4;
        const float* Wrow = (K1 > 0 && k < K1) ? (Wa + (size_t)k * 64) : (Wb + (size_t)(k - K1) * 64);
        float4 v = *(const float4*)(Wrow + c4);
        Wt[(c4 + 0) * KP + k] = f2b(v.x);
        Wt[(c4 + 1) * KP + k] = f2b(v.y);
        Wt[(c4 + 2) * KP + k] = f2b(v.z);
        Wt[(c4 + 3) * KP + k] = f2b(v.w);
    }
    __syncthreads();

    const int w = tid >> 6, lane = tid & 63;
    const int lr = lane & 15, kg = lane >> 4;
    f32x4 acc0 = {0.f, 0.f, 0.f, 0.f}, acc1 = acc0, acc2 = acc0, acc3 = acc0;
    const ushort* arow = &Ab[(w * 16 + lr) * KP + kg * 8];
    const ushort* bp0 = &Wt[(0 + lr) * KP + kg * 8];
    const ushort* bp1 = &Wt[(16 + lr) * KP + kg * 8];
    const ushort* bp2 = &Wt[(32 + lr) * KP + kg * 8];
    const ushort* bp3 = &Wt[(48 + lr) * KP + kg * 8];
#pragma unroll
    for (int k0 = 0; k0 < K; k0 += 32) {
        short8_t af = *(const short8_t*)(arow + k0);
        short8_t b0 = *(const short8_t*)(bp0 + k0);
        short8_t b1 = *(const short8_t*)(bp1 + k0);
        short8_t b2 = *(const short8_t*)(bp2 + k0);
        short8_t b3 = *(const short8_t*)(bp3 + k0);
        acc0 = __builtin_amdgcn_mfma_f32_16x16x32_bf16(af, b0, acc0, 0, 0, 0);
        acc1 = __builtin_amdgcn_mfma_f32_16x16x32_bf16(af, b1, acc1, 0, 0, 0);
        acc2 = __builtin_amdgcn_mfma_f32_16x16x32_bf16(af, b2, acc2, 0, 0, 0);
        acc3 = __builtin_amdgcn_mfma_f32_16x16x32_bf16(af, b3, acc3, 0, 0, 0);
    }

    float asr0 = a_s[lr], asr1 = a_s[16 + lr], asr2 = a_s[32 + lr], asr3 = a_s[48 + lr];
    float adr0 = a_d[lr], adr1 = a_d[16 + lr], adr2 = a_d[32 + lr], adr3 = a_d[48 + lr];
    float bb0 = 0.f, bb1 = 0.f, bb2 = 0.f, bb3 = 0.f;
    if (bias) { bb0 = bias[lr]; bb1 = bias[16 + lr]; bb2 = bias[32 + lr]; bb3 = bias[48 + lr]; }

#pragma unroll
    for (int i = 0; i < 4; ++i) {
        int row = row0 + w * 16 + kg * 4 + i;
        float v0 = acc0[i] + bb0;
        float v1 = acc1[i] + bb1;
        float v2 = acc2[i] + bb2;
        float v3 = acc3[i] + bb3;
        float sh0 = fmaf(v0, asr0, v1 * asr1);
        float sh1 = fmaf(v2, asr2, v3 * asr3);
        float dh0 = fmaf(v0, adr0, v1 * adr1);
        float dh1 = fmaf(v2, adr2, v3 * adr3);
#pragma unroll
        for (int m = 1; m <= 8; m <<= 1) {
            sh0 += __shfl_xor(sh0, m);
            sh1 += __shfl_xor(sh1, m);
            dh0 += __shfl_xor(dh0, m);
            dh1 += __shfl_xor(dh1, m);
        }
        if (row < M) {
            ushort* orow = out + (size_t)row * 64 + lr;
            orow[0]  = f2b(v0);
            orow[16] = f2b(v1);
            orow[32] = f2b(v2);
            orow[48] = f2b(v3);
            if (lr == 0) {
                as2[row] = make_float2(sh0, sh1);
                ad2[row] = make_float2(dh0, dh1);
            }
        }
    }
}

// ---------------- GAT aggregation (16-edge unrolled main iteration) ----------------

template <int DO_LN>
__global__ __launch_bounds__(TPB) void k_agg(const int* __restrict__ offs, const int* __restrict__ csr_src,
                                             const ushort* __restrict__ hb,
                                             const float2* __restrict__ as2,
                                             const float2* __restrict__ ad2,
                                             const float* __restrict__ bias,
                                             const float* __restrict__ ln_g,
                                             const float* __restrict__ ln_b,
                                             void* __restrict__ out_v, int M) {
    __shared__ uint2 ep[4][64];
    int w = (blockIdx.x * blockDim.x + threadIdx.x) >> 6;
    int lane = threadIdx.x & 63;
    int wl = threadIdx.x >> 6;
    if (w >= M) return;
    const int sub = lane & 15;
    const int grp = lane >> 4;
    const int c0 = sub * 4;
    const int head = sub >> 3;
    const int hshift = head << 4;

    float2 adv = ad2[w];
    int beg = offs[w], end = offs[w + 1];
    f32x2 acc01 = {0.f, 0.f}, acc23 = {0.f, 0.f};
    float qs = 0.f;

    for (int base = beg; base < end; base += 64) {
        int nk = end - base;
        if (nk > 64) nk = 64;
        int sidx = csr_src[base + (lane < nk ? lane : 0)];
        float2 av = as2[sidx];
        float e0 = av.x + adv.x; e0 = e0 > 0.f ? e0 : 0.2f * e0;
        float e1 = av.y + adv.y; e1 = e1 > 0.f ? e1 : 0.2f * e1;
        float p0 = __expf(e0), p1 = __expf(e1);
        if (lane >= nk) { p0 = 0.f; p1 = 0.f; }
        ep[wl][lane] = make_uint2((uint32_t)sidx, pack_f16x2(p0, p1));

        int j = 0;
        // 16 edges / iteration: 4 gathers in flight per lane (MLP), avg node (deg~16) = 1 iter
        for (; j + 16 <= nk; j += 16) {
            uint2 eA = ep[wl][j + grp];
            uint2 eB = ep[wl][j + 4 + grp];
            uint2 eC = ep[wl][j + 8 + grp];
            uint2 eD = ep[wl][j + 12 + grp];
            uint2 uA = *(const uint2*)(hb + ((uint32_t)eA.x << 6) + c0);
            uint2 uB = *(const uint2*)(hb + ((uint32_t)eB.x << 6) + c0);
            uint2 uC = *(const uint2*)(hb + ((uint32_t)eC.x << 6) + c0);
            uint2 uD = *(const uint2*)(hb + ((uint32_t)eD.x << 6) + c0);
            float qA = f16lo2f(eA.y >> hshift);
            float qB = f16lo2f(eB.y >> hshift);
            float qC = f16lo2f(eC.y >> hshift);
            float qD = f16lo2f(eD.y >> hshift);
            qs += qA + qB + qC + qD;
            f32x2 hA01 = {b2f_lo(uA.x), b2f_hi(uA.x)};
            f32x2 hA23 = {b2f_lo(uA.y), b2f_hi(uA.y)};
            f32x2 hB01 = {b2f_lo(uB.x), b2f_hi(uB.x)};
            f32x2 hB23 = {b2f_lo(uB.y), b2f_hi(uB.y)};
            f32x2 hC01 = {b2f_lo(uC.x), b2f_hi(uC.x)};
            f32x2 hC23 = {b2f_lo(uC.y), b2f_hi(uC.y)};
            f32x2 hD01 = {b2f_lo(uD.x), b2f_hi(uD.x)};
            f32x2 hD23 = {b2f_lo(uD.y), b2f_hi(uD.y)};
            acc01 += qA * hA01;
            acc23 += qA * hA23;
            acc01 += qB * hB01;
            acc23 += qB * hB23;
            acc01 += qC * hC01;
            acc23 += qC * hC23;
            acc01 += qD * hD01;
            acc23 += qD * hD23;
        }
        for (; j + 8 <= nk; j += 8) {
            uint2 eA = ep[wl][j + grp];
            uint2 eB = ep[wl][j + 4 + grp];
            uint2 uA = *(const uint2*)(hb + ((uint32_t)eA.x << 6) + c0);
            uint2 uB = *(const uint2*)(hb + ((uint32_t)eB.x << 6) + c0);
            float qA = f16lo2f(eA.y >> hshift);
            float qB = f16lo2f(eB.y >> hshift);
            qs += qA + qB;
            f32x2 hA01 = {b2f_lo(uA.x), b2f_hi(uA.x)};
            f32x2 hA23 = {b2f_lo(uA.y), b2f_hi(uA.y)};
            f32x2 hB01 = {b2f_lo(uB.x), b2f_hi(uB.x)};
            f32x2 hB23 = {b2f_lo(uB.y), b2f_hi(uB.y)};
            acc01 += qA * hA01;
            acc23 += qA * hA23;
            acc01 += qB * hB01;
            acc23 += qB * hB23;
        }
        for (; j < nk; j += 4) {
            int src = j + grp;
            if (src > 63) src = 63;
            uint2 e = ep[wl][src];
            uint2 u = *(const uint2*)(hb + ((uint32_t)e.x << 6) + c0);
            float q = f16lo2f(e.y >> hshift);
            qs += q;
            f32x2 h01 = {b2f_lo(u.x), b2f_hi(u.x)};
            f32x2 h23 = {b2f_lo(u.y), b2f_hi(u.y)};
            acc01 += q * h01;
            acc23 += q * h23;
        }
    }
    float a0 = acc01.x, a1 = acc01.y, a2 = acc23.x, a3 = acc23.y;
    a0 += __shfl_xor(a0, 16); a0 += __shfl_xor(a0, 32);
    a1 += __shfl_xor(a1, 16); a1 += __shfl_xor(a1, 32);
    a2 += __shfl_xor(a2, 16); a2 += __shfl_xor(a2, 32);
    a3 += __shfl_xor(a3, 16); a3 += __shfl_xor(a3, 32);
    qs += __shfl_xor(qs, 16); qs += __shfl_xor(qs, 32);

    float inv = 1.f / (qs + 1e-16f);
    float4 bb = *(const float4*)(bias + c0);
    float o0 = fmaf(a0, inv, bb.x);
    float o1 = fmaf(a1, inv, bb.y);
    float o2 = fmaf(a2, inv, bb.z);
    float o3 = fmaf(a3, inv, bb.w);
    o0 = o0 > 0.f ? o0 : expm1f(o0);
    o1 = o1 > 0.f ? o1 : expm1f(o1);
    o2 = o2 > 0.f ? o2 : expm1f(o2);
    o3 = o3 > 0.f ? o3 : expm1f(o3);

    if (DO_LN) {
        float mu = o0 + o1 + o2 + o3;
#pragma unroll
        for (int m = 1; m <= 8; m <<= 1) mu += __shfl_xor(mu, m);
        mu *= (1.f / 64.f);
        float dv = (o0 - mu) * (o0 - mu) + (o1 - mu) * (o1 - mu)
                 + (o2 - mu) * (o2 - mu) + (o3 - mu) * (o3 - mu);
#pragma unroll
        for (int m = 1; m <= 8; m <<= 1) dv += __shfl_xor(dv, m);
        dv *= (1.f / 64.f);
        float rs = rsqrtf(dv + 1e-5f);
        float4 g = *(const float4*)(ln_g + c0);
        float4 b = *(const float4*)(ln_b + c0);
        o0 = (o0 - mu) * rs * g.x + b.x;
        o1 = (o1 - mu) * rs * g.y + b.y;
        o2 = (o2 - mu) * rs * g.z + b.z;
        o3 = (o3 - mu) * rs * g.w + b.w;
        if (lane < 16) {
            float4* out = (float4*)out_v;
            out[(size_t)w * 16 + sub] = make_float4(o0, o1, o2, o3);
        }
    } else {
        if (lane < 16) {
            uint2 pk2;
            pk2.x = (uint32_t)f2b(o0) | ((uint32_t)f2b(o1) << 16);
            pk2.y = (uint32_t)f2b(o2) | ((uint32_t)f2b(o3) << 16);
            uint2* out = (uint2*)out_v;
            out[(size_t)w * 16 + sub] = pk2;
        }
    }
}

// ---------------- launcher ----------------

extern "C" void kernel_launch(void* const* d_in, const int* in_sizes, int n_in,
                              void* d_out, int out_size, void* d_ws, size_t ws_size,
                              hipStream_t stream) {
    const float* x      = (const float*)d_in[0];
    const float* eig    = (const float*)d_in[1];
    const int*   ei     = (const int*)d_in[2];
    const float* phi_w1 = (const float*)d_in[3];
    const float* phi_b1 = (const float*)d_in[4];
    const float* phi_w2 = (const float*)d_in[5];
    const float* phi_b2 = (const float*)d_in[6];
    const float* rho_w  = (const float*)d_in[7];
    const float* rho_b  = (const float*)d_in[8];
    const float* W0     = (const float*)d_in[9];
    const float* asrc0  = (const float*)d_in[10];
    const float* adst0  = (const float*)d_in[11];
    const float* b0     = (const float*)d_in[12];
    const float* W1     = (const float*)d_in[13];
    const float* asrc1  = (const float*)d_in[14];
    const float* adst1  = (const float*)d_in[15];
    const float* b1     = (const float*)d_in[16];
    const float* ln_g   = (const float*)d_in[17];
    const float* ln_b   = (const float*)d_in[18];

    const int N = in_sizes[0] / 128;
    const int E = in_sizes[2] / 2;
    const int* esrc = ei;
    const int* edst = ei + E;

    const int NB   = (N >> 8) + 1;
    const int NBLK = (E + TILE - 1) / TILE;

    auto alignup = [](size_t v) { return (v + 255) & ~(size_t)255; };
    char* w = (char*)d_ws;
    int* S      = (int*)w; w += alignup((size_t)NB * NBLK * 4);
    int* bsum   = (int*)w; w += alignup(4096);
    int* part   = (int*)w; w += alignup((size_t)E * 4);
    int* offs   = (int*)w; w += alignup((size_t)(N + 1) * 4);
    int* csr    = (int*)w; w += alignup((size_t)E * 4);
    ushort* Sb  = (ushort*)w; w += alignup((size_t)N * 64 * 2);
    ushort* hb  = (ushort*)w; w += alignup((size_t)N * 64 * 2);
    ushort* g0b = (ushort*)w; w += alignup((size_t)N * 64 * 2);
    float2* as2 = (float2*)w; w += alignup((size_t)N * 8);
    float2* ad2 = (float2*)w; w += alignup((size_t)N * 8);
    float* R    = (float*)w; w += alignup(64 * 64 * 4);
    float* cvec = (float*)w; w += alignup(64 * 4);

    // ---- CSR build ----
    const int tot = NB * NBLK;
    const int nbS = (tot + 1023) / 1024;
    k_hist<<<NBLK, TPB, 0, stream>>>(edst, S, E, NB, NBLK);
    k_scan1<<<nbS, TPB, 0, stream>>>(S, bsum, tot);
    k_scan2<<<1, 256, 0, stream>>>(bsum, nbS);
    k_scan3<<<nbS, TPB, 0, stream>>>(S, bsum, tot);
    k_part<<<NBLK, TPB, 0, stream>>>(esrc, edst, S, part, E, NB, NBLK);
    k_csr<<<NB, TPB, 0, stream>>>(part, S, offs, csr, E, N, NB, NBLK);

    k_rinit<<<1, TPB, 0, stream>>>(rho_w, rho_b, W0, R, cvec);

    int gM = (N + 63) / 64;
    // ---- SignNet (phi1 VALU + phi2 MFMA) ----
    k_sign<<<gM, TPB, 0, stream>>>(eig, phi_w1, phi_b1, phi_w2, phi_b2, Sb, N);

    // ---- GAT layer 0: MFMA GEMM (K=128 fp32-x | 64 bf16-S), fused alpha ----
    k_mmfma<128, 64><<<gM, TPB, 0, stream>>>(x, Sb, W0, R, cvec, asrc0, adst0, as2, ad2, hb, N);
    int ga = (N + 3) / 4;
    k_agg<0><<<ga, TPB, 0, stream>>>(offs, csr, hb, as2, ad2, b0, nullptr, nullptr, g0b, N);

    // ---- GAT layer 1: MFMA GEMM (K=64 bf16), fused alpha ----
    k_mmfma<0, 64><<<gM, TPB, 0, stream>>>(nullptr, g0b, nullptr, W1, nullptr, asrc1, adst1, as2, ad2, hb, N);
    k_agg<1><<<ga, TPB, 0, stream>>>(offs, csr, hb, as2, ad2, b1, ln_g, ln_b, d_out, N);

    (void)n_in; (void)ws_size; (void)out_size;
}